// Round 1
// baseline (1456.414 us; speedup 1.0000x reference)
//
#include <hip/hip_runtime.h>
#include <hip/hip_bf16.h>

#define EMB 1024
#define SEQ 2048
#define BATCH 4
#define TOK (BATCH*SEQ)
#define NH 16
#define DH 64
#define FF 4096

typedef unsigned short u16;
typedef __bf16 bf16x8 __attribute__((ext_vector_type(8)));
typedef float f32x4 __attribute__((ext_vector_type(4)));

union frag_u { uint4 u4; bf16x8 bf; u16 us[8]; };

__device__ __forceinline__ u16 f2bf(float f) {
  union { float f; unsigned u; } a; a.f = f;
  unsigned r = a.u + 0x7fffu + ((a.u >> 16) & 1u);
  return (u16)(r >> 16);
}

// ---------------- fp32 -> bf16 weight conversion ----------------
__global__ __launch_bounds__(256) void cvt_kernel(const float* __restrict__ src,
                                                  u16* __restrict__ dst, int n4) {
  int i = blockIdx.x * 256 + threadIdx.x;
  if (i >= n4) return;
  float4 v = ((const float4*)src)[i];
  ushort4 o;
  o.x = f2bf(v.x); o.y = f2bf(v.y); o.z = f2bf(v.z); o.w = f2bf(v.w);
  ((ushort4*)dst)[i] = o;
}

// ---------------- LayerNorm (fp32 in -> bf16 out), one wave per row ----------------
__global__ __launch_bounds__(256) void ln_kernel(const float* __restrict__ x,
                                                 const float* __restrict__ g,
                                                 const float* __restrict__ be,
                                                 u16* __restrict__ out) {
  int wave = threadIdx.x >> 6, lane = threadIdx.x & 63;
  int row = blockIdx.x * 4 + wave;
  const float* xr = x + (size_t)row * EMB;
  float4 v[4];
  float s = 0.f;
  #pragma unroll
  for (int i = 0; i < 4; i++) {
    v[i] = *(const float4*)(xr + i * 256 + lane * 4);
    s += v[i].x + v[i].y + v[i].z + v[i].w;
  }
  #pragma unroll
  for (int m = 1; m < 64; m <<= 1) s += __shfl_xor(s, m, 64);
  float mean = s * (1.f / EMB);
  float vs = 0.f;
  #pragma unroll
  for (int i = 0; i < 4; i++) {
    float dx;
    dx = v[i].x - mean; vs += dx * dx;
    dx = v[i].y - mean; vs += dx * dx;
    dx = v[i].z - mean; vs += dx * dx;
    dx = v[i].w - mean; vs += dx * dx;
  }
  #pragma unroll
  for (int m = 1; m < 64; m <<= 1) vs += __shfl_xor(vs, m, 64);
  float inv = rsqrtf(vs * (1.f / EMB) + 1e-5f);
  u16* orow = out + (size_t)row * EMB;
  #pragma unroll
  for (int i = 0; i < 4; i++) {
    int c = i * 256 + lane * 4;
    float4 gv = *(const float4*)(g + c);
    float4 bv = *(const float4*)(be + c);
    ushort4 o;
    o.x = f2bf(gv.x * (v[i].x - mean) * inv + bv.x);
    o.y = f2bf(gv.y * (v[i].y - mean) * inv + bv.y);
    o.z = f2bf(gv.z * (v[i].z - mean) * inv + bv.z);
    o.w = f2bf(gv.w * (v[i].w - mean) * inv + bv.w);
    *(ushort4*)(orow + c) = o;
  }
}

// ---------------- generic 64x64-tile bf16 MFMA GEMM ----------------
// MODE 1: QKV permute-store bf16 [B,H,S,D];  MODE 2: +bias, exact GELU, bf16 out;
// MODE 3: +bias +residual, fp32 out.
template <int MODE>
__global__ __launch_bounds__(256) void gemm64(const u16* __restrict__ A,
                                              const u16* __restrict__ Bw,
                                              const float* __restrict__ bias,
                                              const float* __restrict__ resid,
                                              void* __restrict__ outp,
                                              int M, int N, int K) {
  __shared__ __align__(16) u16 As[64 * 40];
  __shared__ __align__(16) u16 Bs[64 * 40];
  const int t = threadIdx.x;
  const int wave = t >> 6, lane = t & 63;
  const int lane15 = lane & 15, quad = lane >> 4;
  const int rowBase = blockIdx.y * 64, colBase = blockIdx.x * 64;
  const int a_row = t >> 2, a_col = (t & 3) * 8;
  const int b_k = t >> 3, b_n = (t & 7) * 8;
  f32x4 zero = {0.f, 0.f, 0.f, 0.f};
  f32x4 acc[4];
  #pragma unroll
  for (int i = 0; i < 4; i++) acc[i] = zero;

  for (int k0 = 0; k0 < K; k0 += 32) {
    __syncthreads();
    uint4 av = *(const uint4*)(A + (size_t)(rowBase + a_row) * K + k0 + a_col);
    *(uint4*)(As + a_row * 40 + a_col) = av;
    uint4 bv = *(const uint4*)(Bw + (size_t)(k0 + b_k) * N + colBase + b_n);
    const u16* bs = (const u16*)&bv;
    #pragma unroll
    for (int i = 0; i < 8; i++) Bs[(b_n + i) * 40 + b_k] = bs[i];
    __syncthreads();
    frag_u af;
    af.u4 = *(const uint4*)(As + (wave * 16 + lane15) * 40 + quad * 8);
    #pragma unroll
    for (int n0 = 0; n0 < 4; n0++) {
      frag_u bf_;
      bf_.u4 = *(const uint4*)(Bs + (n0 * 16 + lane15) * 40 + quad * 8);
      acc[n0] = __builtin_amdgcn_mfma_f32_16x16x32_bf16(af.bf, bf_.bf, acc[n0], 0, 0, 0);
    }
  }

  #pragma unroll
  for (int n0 = 0; n0 < 4; n0++) {
    #pragma unroll
    for (int r = 0; r < 4; r++) {
      int row = rowBase + wave * 16 + quad * 4 + r;
      int col = colBase + n0 * 16 + lane15;
      float vv = acc[n0][r];
      if (MODE == 1) {
        int b = row >> 11, s = row & 2047;
        int hh = col >> 6, d = col & 63;
        ((u16*)outp)[(((size_t)(b * NH + hh) * SEQ + s) << 6) + d] = f2bf(vv);
      } else if (MODE == 2) {
        vv += bias[col];
        vv = 0.5f * vv * (1.f + erff(vv * 0.70710678118f));
        ((u16*)outp)[(size_t)row * N + col] = f2bf(vv);
      } else {
        vv += bias[col] + resid[(size_t)row * N + col];
        ((float*)outp)[(size_t)row * N + col] = vv;
      }
    }
  }
}

// ---------------- flash attention (causal), 64-row Q tile per block ----------------
__global__ __launch_bounds__(256) void attn_kernel(const u16* __restrict__ q,
                                                   const u16* __restrict__ k,
                                                   const u16* __restrict__ v,
                                                   u16* __restrict__ ctx) {
  __shared__ __align__(16) u16 Qs[64 * 72];
  __shared__ __align__(16) u16 Ks[64 * 72];
  __shared__ __align__(16) u16 Vs[64 * 72];  // transposed: Vs[d][kk]
  __shared__ __align__(16) u16 Ps[4 * 16 * 72];
  const int t = threadIdx.x;
  const int wave = t >> 6, lane = t & 63;
  const int lane15 = lane & 15, quad = lane >> 4;
  const int qt = blockIdx.x, bh = blockIdx.y;
  const size_t base = (size_t)bh * SEQ * DH;
  const int lr = t >> 2, lc = (t & 3) * 16;

  {
    const u16* qp = q + base + (size_t)(qt * 64 + lr) * 64 + lc;
    *(uint4*)(Qs + lr * 72 + lc) = *(const uint4*)(qp);
    *(uint4*)(Qs + lr * 72 + lc + 8) = *(const uint4*)(qp + 8);
  }

  f32x4 zero = {0.f, 0.f, 0.f, 0.f};
  f32x4 oacc[4];
  #pragma unroll
  for (int i = 0; i < 4; i++) oacc[i] = zero;
  float m_r[4], l_r[4];
  #pragma unroll
  for (int r = 0; r < 4; r++) { m_r[r] = -1e30f; l_r[r] = 0.f; }
  u16* PsW = Ps + wave * 16 * 72;

  for (int kt = 0; kt <= qt; kt++) {
    __syncthreads();
    const u16* kp = k + base + (size_t)(kt * 64 + lr) * 64 + lc;
    *(uint4*)(Ks + lr * 72 + lc) = *(const uint4*)(kp);
    *(uint4*)(Ks + lr * 72 + lc + 8) = *(const uint4*)(kp + 8);
    const u16* vp = v + base + (size_t)(kt * 64 + lr) * 64 + lc;
    uint4 v0 = *(const uint4*)(vp);
    uint4 v1 = *(const uint4*)(vp + 8);
    const u16* vs0 = (const u16*)&v0;
    const u16* vs1 = (const u16*)&v1;
    #pragma unroll
    for (int i = 0; i < 8; i++) Vs[(lc + i) * 72 + lr] = vs0[i];
    #pragma unroll
    for (int i = 0; i < 8; i++) Vs[(lc + 8 + i) * 72 + lr] = vs1[i];
    __syncthreads();

    // S = Q K^T
    f32x4 sacc[4];
    #pragma unroll
    for (int i = 0; i < 4; i++) sacc[i] = zero;
    #pragma unroll
    for (int ks = 0; ks < 64; ks += 32) {
      frag_u af;
      af.u4 = *(const uint4*)(Qs + (wave * 16 + lane15) * 72 + ks + quad * 8);
      #pragma unroll
      for (int n0 = 0; n0 < 4; n0++) {
        frag_u bf_;
        bf_.u4 = *(const uint4*)(Ks + (n0 * 16 + lane15) * 72 + ks + quad * 8);
        sacc[n0] = __builtin_amdgcn_mfma_f32_16x16x32_bf16(af.bf, bf_.bf, sacc[n0], 0, 0, 0);
      }
    }

    // online softmax per row (row = quad*4 + r)
    #pragma unroll
    for (int r = 0; r < 4; r++) {
      int qrow = qt * 64 + wave * 16 + quad * 4 + r;
      float mx = -1e30f;
      #pragma unroll
      for (int n0 = 0; n0 < 4; n0++) {
        int kcol = kt * 64 + n0 * 16 + lane15;
        float sv = sacc[n0][r] * 0.125f;
        if (kcol > qrow) sv = -1e30f;
        sacc[n0][r] = sv;
        mx = fmaxf(mx, sv);
      }
      #pragma unroll
      for (int off = 1; off < 16; off <<= 1) mx = fmaxf(mx, __shfl_xor(mx, off, 64));
      float mnew = fmaxf(m_r[r], mx);
      float alpha = __expf(m_r[r] - mnew);
      m_r[r] = mnew;
      float ps = 0.f;
      #pragma unroll
      for (int n0 = 0; n0 < 4; n0++) {
        float p = __expf(sacc[n0][r] - mnew);
        sacc[n0][r] = p;
        ps += p;
      }
      #pragma unroll
      for (int off = 1; off < 16; off <<= 1) ps += __shfl_xor(ps, off, 64);
      l_r[r] = l_r[r] * alpha + ps;
      #pragma unroll
      for (int n0 = 0; n0 < 4; n0++) oacc[n0][r] *= alpha;
      #pragma unroll
      for (int n0 = 0; n0 < 4; n0++)
        PsW[(quad * 4 + r) * 72 + n0 * 16 + lane15] = f2bf(sacc[n0][r]);
    }

    // O += P V  (P from LDS in A-layout, V^T rows contiguous)
    #pragma unroll
    for (int ks = 0; ks < 64; ks += 32) {
      frag_u af;
      af.u4 = *(const uint4*)(PsW + lane15 * 72 + ks + quad * 8);
      #pragma unroll
      for (int n0 = 0; n0 < 4; n0++) {
        frag_u bf_;
        bf_.u4 = *(const uint4*)(Vs + (n0 * 16 + lane15) * 72 + ks + quad * 8);
        oacc[n0] = __builtin_amdgcn_mfma_f32_16x16x32_bf16(af.bf, bf_.bf, oacc[n0], 0, 0, 0);
      }
    }
  }

  // epilogue: ctx[b*S+s][h*64+d] bf16
  int bq = bh >> 4, hh = bh & 15;
  float inv_l[4];
  #pragma unroll
  for (int r = 0; r < 4; r++) inv_l[r] = 1.f / l_r[r];
  #pragma unroll
  for (int n0 = 0; n0 < 4; n0++) {
    #pragma unroll
    for (int r = 0; r < 4; r++) {
      int s = qt * 64 + wave * 16 + quad * 4 + r;
      int col = hh * 64 + n0 * 16 + lane15;
      ctx[((size_t)(bq * SEQ + s)) * EMB + col] = f2bf(oacc[n0][r] * inv_l[r]);
    }
  }
}

extern "C" void kernel_launch(void* const* d_in, const int* in_sizes, int n_in,
                              void* d_out, int out_size, void* d_ws, size_t ws_size,
                              hipStream_t stream) {
  const float* x  = (const float*)d_in[0];
  const float* Wq = (const float*)d_in[1];
  const float* Wk = (const float*)d_in[2];
  const float* Wv = (const float*)d_in[3];
  const float* Wo = (const float*)d_in[4];
  const float* bo = (const float*)d_in[5];
  const float* W1 = (const float*)d_in[6];
  const float* b1 = (const float*)d_in[7];
  const float* W2 = (const float*)d_in[8];
  const float* b2 = (const float*)d_in[9];
  const float* g1  = (const float*)d_in[10];
  const float* be1 = (const float*)d_in[11];
  const float* g2  = (const float*)d_in[12];
  const float* be2 = (const float*)d_in[13];
  float* out = (float*)d_out;
  char* ws = (char*)d_ws;
  const size_t MB = 1u << 20;

  // workspace layout (136 MB total, with liveness-based reuse):
  u16* wq_b = (u16*)(ws + 0 * MB);
  u16* wk_b = (u16*)(ws + 2 * MB);
  u16* wv_b = (u16*)(ws + 4 * MB);
  u16* wo_b = (u16*)(ws + 6 * MB);
  u16* w1_b = (u16*)(ws + 8 * MB);
  u16* w2_b = (u16*)(ws + 16 * MB);
  float* hbuf = (float*)(ws + 24 * MB);       // 32 MB fp32 residual h
  u16* r1 = (u16*)(ws + 56 * MB);             // 16 MB: xn1 -> ctx -> xn2
  u16* qb = (u16*)(ws + 72 * MB);             // 16 MB
  u16* kb = (u16*)(ws + 88 * MB);             // 16 MB
  u16* vb = (u16*)(ws + 104 * MB);            // 16 MB
  u16* f1 = (u16*)(ws + 72 * MB);             // 64 MB, overlaps q/k/v (dead after attn)

  // 1. weights -> bf16
  cvt_kernel<<<1024, 256, 0, stream>>>(Wq, wq_b, 262144);
  cvt_kernel<<<1024, 256, 0, stream>>>(Wk, wk_b, 262144);
  cvt_kernel<<<1024, 256, 0, stream>>>(Wv, wv_b, 262144);
  cvt_kernel<<<1024, 256, 0, stream>>>(Wo, wo_b, 262144);
  cvt_kernel<<<4096, 256, 0, stream>>>(W1, w1_b, 1048576);
  cvt_kernel<<<4096, 256, 0, stream>>>(W2, w2_b, 1048576);

  // 2. LN1(x) -> xn1 (bf16)
  ln_kernel<<<2048, 256, 0, stream>>>(x, g1, be1, r1);

  // 3. QKV projections -> [B,H,S,D] bf16
  dim3 g16(16, 128);
  gemm64<1><<<g16, 256, 0, stream>>>(r1, wq_b, nullptr, nullptr, qb, TOK, EMB, EMB);
  gemm64<1><<<g16, 256, 0, stream>>>(r1, wk_b, nullptr, nullptr, kb, TOK, EMB, EMB);
  gemm64<1><<<g16, 256, 0, stream>>>(r1, wv_b, nullptr, nullptr, vb, TOK, EMB, EMB);

  // 4. causal flash attention -> ctx (bf16, reuses r1)
  attn_kernel<<<dim3(32, 64), 256, 0, stream>>>(qb, kb, vb, r1);

  // 5. Wo projection + bo + x -> h (fp32)
  gemm64<3><<<g16, 256, 0, stream>>>(r1, wo_b, bo, x, hbuf, TOK, EMB, EMB);

  // 6. LN2(h) -> xn2 (bf16, reuses r1)
  ln_kernel<<<2048, 256, 0, stream>>>(hbuf, g2, be2, r1);

  // 7. FFN1: GELU(xn2 @ W1 + b1) -> f1 (bf16)
  gemm64<2><<<dim3(64, 128), 256, 0, stream>>>(r1, w1_b, b1, nullptr, f1, TOK, FF, EMB);

  // 8. FFN2: f1 @ W2 + b2 + h -> out (fp32)
  gemm64<3><<<g16, 256, 0, stream>>>(f1, w2_b, b2, hbuf, out, TOK, EMB, FF);
}

// Round 2
// 748.156 us; speedup vs baseline: 1.9467x; 1.9467x over previous
//
#include <hip/hip_runtime.h>
#include <hip/hip_bf16.h>

#define EMB 1024
#define SEQ 2048
#define BATCH 4
#define TOK (BATCH*SEQ)
#define NH 16
#define DH 64
#define FF 4096

typedef unsigned short u16;
typedef __bf16 bf16x8 __attribute__((ext_vector_type(8)));
typedef float f32x4 __attribute__((ext_vector_type(4)));

union frag_u { uint4 u4; bf16x8 bf; u16 us[8]; };

__device__ __forceinline__ u16 f2bf(float f) {
  union { float f; unsigned u; } a; a.f = f;
  unsigned r = a.u + 0x7fffu + ((a.u >> 16) & 1u);
  return (u16)(r >> 16);
}

__device__ __forceinline__ void glds16(const void* g, void* l) {
  __builtin_amdgcn_global_load_lds((const __attribute__((address_space(1))) void*)g,
                                   (__attribute__((address_space(3))) void*)l, 16, 0, 0);
}

// ---------------- fp32 [K][N] -> bf16 [N][ldk] transpose+convert ----------------
__global__ __launch_bounds__(256) void cvt_t_kernel(const float* __restrict__ src,
                                                    u16* __restrict__ dst,
                                                    int N, int ldk) {
  __shared__ float tile[32][33];
  int c0 = blockIdx.x * 32, r0 = blockIdx.y * 32;
  int tc = threadIdx.x & 31, tr = threadIdx.x >> 5;  // tr 0..7
  #pragma unroll
  for (int p = 0; p < 4; p++)
    tile[tr + p * 8][tc] = src[(size_t)(r0 + tr + p * 8) * N + c0 + tc];
  __syncthreads();
  #pragma unroll
  for (int p = 0; p < 4; p++)
    dst[(size_t)(c0 + tr + p * 8) * ldk + r0 + tc] = f2bf(tile[tc][tr + p * 8]);
}

// ---------------- LayerNorm (fp32 in -> bf16 out), one wave per row ----------------
__global__ __launch_bounds__(256) void ln_kernel(const float* __restrict__ x,
                                                 const float* __restrict__ g,
                                                 const float* __restrict__ be,
                                                 u16* __restrict__ out) {
  int wave = threadIdx.x >> 6, lane = threadIdx.x & 63;
  int row = blockIdx.x * 4 + wave;
  const float* xr = x + (size_t)row * EMB;
  float4 v[4];
  float s = 0.f;
  #pragma unroll
  for (int i = 0; i < 4; i++) {
    v[i] = *(const float4*)(xr + i * 256 + lane * 4);
    s += v[i].x + v[i].y + v[i].z + v[i].w;
  }
  #pragma unroll
  for (int m = 1; m < 64; m <<= 1) s += __shfl_xor(s, m, 64);
  float mean = s * (1.f / EMB);
  float vs = 0.f;
  #pragma unroll
  for (int i = 0; i < 4; i++) {
    float dx;
    dx = v[i].x - mean; vs += dx * dx;
    dx = v[i].y - mean; vs += dx * dx;
    dx = v[i].z - mean; vs += dx * dx;
    dx = v[i].w - mean; vs += dx * dx;
  }
  #pragma unroll
  for (int m = 1; m < 64; m <<= 1) vs += __shfl_xor(vs, m, 64);
  float inv = rsqrtf(vs * (1.f / EMB) + 1e-5f);
  u16* orow = out + (size_t)row * EMB;
  #pragma unroll
  for (int i = 0; i < 4; i++) {
    int c = i * 256 + lane * 4;
    float4 gv = *(const float4*)(g + c);
    float4 bv = *(const float4*)(be + c);
    ushort4 o;
    o.x = f2bf(gv.x * (v[i].x - mean) * inv + bv.x);
    o.y = f2bf(gv.y * (v[i].y - mean) * inv + bv.y);
    o.z = f2bf(gv.z * (v[i].z - mean) * inv + bv.z);
    o.w = f2bf(gv.w * (v[i].w - mean) * inv + bv.w);
    *(ushort4*)(orow + c) = o;
  }
}

// ---------------- m97-structure 128x128 bf16 MFMA GEMM, B^T input ----------------
// A: [M][K] bf16, Bt: [N][K] bf16. 4 waves, each 64x64 (4x4 of 16x16x32).
// MODE 1: fused-QKV permute-store bf16 [3][B,H,S,D]
// MODE 2: +bias, exact GELU, bf16 out row-major
// MODE 3: +bias +residual, fp32 out row-major
template <int MODE>
__global__ __launch_bounds__(256) void gemm128(const u16* __restrict__ A,
                                               const u16* __restrict__ Bt,
                                               const float* __restrict__ bias,
                                               const float* __restrict__ resid,
                                               void* __restrict__ outp,
                                               int N, int K) {
  __shared__ __align__(16) u16 As[128 * 32];   // [row][k] unpadded (glds layout)
  __shared__ __align__(16) u16 Bs[128 * 32];   // [col][k] unpadded
  const int t = threadIdx.x;
  const int w = t >> 6, lane = t & 63;
  const int lane15 = lane & 15, quad = lane >> 4;
  const int wr = w >> 1, wc = w & 1;
  const int rowBase = blockIdx.y * 128, colBase = blockIdx.x * 128;

  // staging: wave w covers rows [w*32, w*32+32) of each tile; 2 issues of 16B/lane
  const int s_row = w * 32 + (lane >> 2);      // + j*16
  const int s_col = (lane & 3) * 8;
  const u16* gA = A + (size_t)(rowBase + s_row) * K + s_col;
  const u16* gB = Bt + (size_t)(colBase + s_row) * K + s_col;
  u16* lA = As + w * 1024;                     // lane*16B appended by HW
  u16* lB = Bs + w * 1024;

  f32x4 zero = {0.f, 0.f, 0.f, 0.f};
  f32x4 acc[4][4];
  #pragma unroll
  for (int i = 0; i < 4; i++)
    #pragma unroll
    for (int j = 0; j < 4; j++) acc[i][j] = zero;

  for (int k0 = 0; k0 < K; k0 += 32) {
    __syncthreads();
    glds16(gA + k0, lA);
    glds16(gA + (size_t)16 * K + k0, lA + 512);
    glds16(gB + k0, lB);
    glds16(gB + (size_t)16 * K + k0, lB + 512);
    __syncthreads();
    frag_u a4[4], b4[4];
    #pragma unroll
    for (int mi = 0; mi < 4; mi++)
      a4[mi].u4 = *(const uint4*)(As + (wr * 64 + mi * 16 + lane15) * 32 + quad * 8);
    #pragma unroll
    for (int ni = 0; ni < 4; ni++)
      b4[ni].u4 = *(const uint4*)(Bs + (wc * 64 + ni * 16 + lane15) * 32 + quad * 8);
    #pragma unroll
    for (int mi = 0; mi < 4; mi++)
      #pragma unroll
      for (int ni = 0; ni < 4; ni++)
        acc[mi][ni] = __builtin_amdgcn_mfma_f32_16x16x32_bf16(a4[mi].bf, b4[ni].bf, acc[mi][ni], 0, 0, 0);
  }

  #pragma unroll
  for (int mi = 0; mi < 4; mi++) {
    #pragma unroll
    for (int ni = 0; ni < 4; ni++) {
      #pragma unroll
      for (int r = 0; r < 4; r++) {
        int row = rowBase + wr * 64 + mi * 16 + quad * 4 + r;
        int col = colBase + wc * 64 + ni * 16 + lane15;
        float vv = acc[mi][ni][r];
        if (MODE == 1) {
          int mat = col >> 10, cc = col & 1023;
          int hh = cc >> 6, d = cc & 63;
          int b = row >> 11, s = row & 2047;
          ((u16*)outp)[(size_t)mat * (TOK * EMB) +
                       (((size_t)(b * NH + hh) * SEQ + s) << 6) + d] = f2bf(vv);
        } else if (MODE == 2) {
          vv += bias[col];
          vv = 0.5f * vv * (1.f + erff(vv * 0.70710678118f));
          ((u16*)outp)[(size_t)row * N + col] = f2bf(vv);
        } else {
          vv += bias[col] + resid[(size_t)row * N + col];
          ((float*)outp)[(size_t)row * N + col] = vv;
        }
      }
    }
  }
}

// ---------------- flash attention (causal), 64-row Q tile per block ----------------
__global__ __launch_bounds__(256) void attn_kernel(const u16* __restrict__ q,
                                                   const u16* __restrict__ k,
                                                   const u16* __restrict__ v,
                                                   u16* __restrict__ ctx) {
  __shared__ __align__(16) u16 Qs[64 * 72];
  __shared__ __align__(16) u16 Ks[64 * 72];
  __shared__ __align__(16) u16 Vs[64 * 72];  // transposed: Vs[d][kk]
  __shared__ __align__(16) u16 Ps[4 * 16 * 72];
  const int t = threadIdx.x;
  const int wave = t >> 6, lane = t & 63;
  const int lane15 = lane & 15, quad = lane >> 4;
  const int qt = blockIdx.x, bh = blockIdx.y;
  const size_t base = (size_t)bh * SEQ * DH;
  const int lr = t >> 2, lc = (t & 3) * 16;

  {
    const u16* qp = q + base + (size_t)(qt * 64 + lr) * 64 + lc;
    *(uint4*)(Qs + lr * 72 + lc) = *(const uint4*)(qp);
    *(uint4*)(Qs + lr * 72 + lc + 8) = *(const uint4*)(qp + 8);
  }

  f32x4 zero = {0.f, 0.f, 0.f, 0.f};
  f32x4 oacc[4];
  #pragma unroll
  for (int i = 0; i < 4; i++) oacc[i] = zero;
  float m_r[4], l_r[4];
  #pragma unroll
  for (int r = 0; r < 4; r++) { m_r[r] = -1e30f; l_r[r] = 0.f; }
  u16* PsW = Ps + wave * 16 * 72;

  for (int kt = 0; kt <= qt; kt++) {
    __syncthreads();
    const u16* kp = k + base + (size_t)(kt * 64 + lr) * 64 + lc;
    *(uint4*)(Ks + lr * 72 + lc) = *(const uint4*)(kp);
    *(uint4*)(Ks + lr * 72 + lc + 8) = *(const uint4*)(kp + 8);
    const u16* vp = v + base + (size_t)(kt * 64 + lr) * 64 + lc;
    uint4 v0 = *(const uint4*)(vp);
    uint4 v1 = *(const uint4*)(vp + 8);
    const u16* vs0 = (const u16*)&v0;
    const u16* vs1 = (const u16*)&v1;
    #pragma unroll
    for (int i = 0; i < 8; i++) Vs[(lc + i) * 72 + lr] = vs0[i];
    #pragma unroll
    for (int i = 0; i < 8; i++) Vs[(lc + 8 + i) * 72 + lr] = vs1[i];
    __syncthreads();

    f32x4 sacc[4];
    #pragma unroll
    for (int i = 0; i < 4; i++) sacc[i] = zero;
    #pragma unroll
    for (int ks = 0; ks < 64; ks += 32) {
      frag_u af;
      af.u4 = *(const uint4*)(Qs + (wave * 16 + lane15) * 72 + ks + quad * 8);
      #pragma unroll
      for (int n0 = 0; n0 < 4; n0++) {
        frag_u bf_;
        bf_.u4 = *(const uint4*)(Ks + (n0 * 16 + lane15) * 72 + ks + quad * 8);
        sacc[n0] = __builtin_amdgcn_mfma_f32_16x16x32_bf16(af.bf, bf_.bf, sacc[n0], 0, 0, 0);
      }
    }

    #pragma unroll
    for (int r = 0; r < 4; r++) {
      int qrow = qt * 64 + wave * 16 + quad * 4 + r;
      float mx = -1e30f;
      #pragma unroll
      for (int n0 = 0; n0 < 4; n0++) {
        int kcol = kt * 64 + n0 * 16 + lane15;
        float sv = sacc[n0][r] * 0.125f;
        if (kcol > qrow) sv = -1e30f;
        sacc[n0][r] = sv;
        mx = fmaxf(mx, sv);
      }
      #pragma unroll
      for (int off = 1; off < 16; off <<= 1) mx = fmaxf(mx, __shfl_xor(mx, off, 64));
      float mnew = fmaxf(m_r[r], mx);
      float alpha = __expf(m_r[r] - mnew);
      m_r[r] = mnew;
      float ps = 0.f;
      #pragma unroll
      for (int n0 = 0; n0 < 4; n0++) {
        float p = __expf(sacc[n0][r] - mnew);
        sacc[n0][r] = p;
        ps += p;
      }
      #pragma unroll
      for (int off = 1; off < 16; off <<= 1) ps += __shfl_xor(ps, off, 64);
      l_r[r] = l_r[r] * alpha + ps;
      #pragma unroll
      for (int n0 = 0; n0 < 4; n0++) oacc[n0][r] *= alpha;
      #pragma unroll
      for (int n0 = 0; n0 < 4; n0++)
        PsW[(quad * 4 + r) * 72 + n0 * 16 + lane15] = f2bf(sacc[n0][r]);
    }

    #pragma unroll
    for (int ks = 0; ks < 64; ks += 32) {
      frag_u af;
      af.u4 = *(const uint4*)(PsW + lane15 * 72 + ks + quad * 8);
      #pragma unroll
      for (int n0 = 0; n0 < 4; n0++) {
        frag_u bf_;
        bf_.u4 = *(const uint4*)(Vs + (n0 * 16 + lane15) * 72 + ks + quad * 8);
        oacc[n0] = __builtin_amdgcn_mfma_f32_16x16x32_bf16(af.bf, bf_.bf, oacc[n0], 0, 0, 0);
      }
    }
  }

  int bq = bh >> 4, hh = bh & 15;
  float inv_l[4];
  #pragma unroll
  for (int r = 0; r < 4; r++) inv_l[r] = 1.f / l_r[r];
  #pragma unroll
  for (int n0 = 0; n0 < 4; n0++) {
    #pragma unroll
    for (int r = 0; r < 4; r++) {
      int s = qt * 64 + wave * 16 + quad * 4 + r;
      int col = hh * 64 + n0 * 16 + lane15;
      ctx[((size_t)(bq * SEQ + s)) * EMB + col] = f2bf(oacc[n0][r] * inv_l[r]);
    }
  }
}

extern "C" void kernel_launch(void* const* d_in, const int* in_sizes, int n_in,
                              void* d_out, int out_size, void* d_ws, size_t ws_size,
                              hipStream_t stream) {
  const float* x  = (const float*)d_in[0];
  const float* Wq = (const float*)d_in[1];
  const float* Wk = (const float*)d_in[2];
  const float* Wv = (const float*)d_in[3];
  const float* Wo = (const float*)d_in[4];
  const float* bo = (const float*)d_in[5];
  const float* W1 = (const float*)d_in[6];
  const float* b1 = (const float*)d_in[7];
  const float* W2 = (const float*)d_in[8];
  const float* b2 = (const float*)d_in[9];
  const float* g1  = (const float*)d_in[10];
  const float* be1 = (const float*)d_in[11];
  const float* g2  = (const float*)d_in[12];
  const float* be2 = (const float*)d_in[13];
  float* out = (float*)d_out;
  char* ws = (char*)d_ws;
  const size_t MB = 1u << 20;

  // workspace (136 MB):
  u16* wqkv_t = (u16*)(ws + 0 * MB);          // [3072][1024] bf16, 6 MB
  u16* wo_t   = (u16*)(ws + 6 * MB);          // [1024][1024], 2 MB
  u16* w1_t   = (u16*)(ws + 8 * MB);          // [4096][1024], 8 MB
  u16* w2_t   = (u16*)(ws + 16 * MB);         // [1024][4096], 8 MB
  float* hbuf = (float*)(ws + 24 * MB);       // 32 MB fp32 residual h
  u16* r1 = (u16*)(ws + 56 * MB);             // 16 MB: xn1 -> ctx -> xn2
  u16* qb = (u16*)(ws + 72 * MB);             // q,k,v contiguous 48 MB [B,H,S,D] each
  u16* kb = (u16*)(ws + 88 * MB);
  u16* vb = (u16*)(ws + 104 * MB);
  u16* f1 = (u16*)(ws + 72 * MB);             // 64 MB, overlaps q/k/v (dead after attn)

  // 1. weights -> bf16 transposed [N][K]
  cvt_t_kernel<<<dim3(32, 32), 256, 0, stream>>>(Wq, wqkv_t, 1024, 1024);
  cvt_t_kernel<<<dim3(32, 32), 256, 0, stream>>>(Wk, wqkv_t + 1024 * 1024, 1024, 1024);
  cvt_t_kernel<<<dim3(32, 32), 256, 0, stream>>>(Wv, wqkv_t + 2 * 1024 * 1024, 1024, 1024);
  cvt_t_kernel<<<dim3(32, 32), 256, 0, stream>>>(Wo, wo_t, 1024, 1024);
  cvt_t_kernel<<<dim3(128, 32), 256, 0, stream>>>(W1, w1_t, 4096, 1024);
  cvt_t_kernel<<<dim3(32, 128), 256, 0, stream>>>(W2, w2_t, 1024, 4096);

  // 2. LN1(x) -> xn1 (bf16)
  ln_kernel<<<2048, 256, 0, stream>>>(x, g1, be1, r1);

  // 3. fused QKV projection -> q,k,v [B,H,S,D] bf16
  gemm128<1><<<dim3(24, 64), 256, 0, stream>>>(r1, wqkv_t, nullptr, nullptr, qb, 3072, 1024);

  // 4. causal flash attention -> ctx (bf16, reuses r1)
  attn_kernel<<<dim3(32, 64), 256, 0, stream>>>(qb, kb, vb, r1);

  // 5. Wo projection + bo + x -> h (fp32)
  gemm128<3><<<dim3(8, 64), 256, 0, stream>>>(r1, wo_t, bo, x, hbuf, 1024, 1024);

  // 6. LN2(h) -> xn2 (bf16, reuses r1)
  ln_kernel<<<2048, 256, 0, stream>>>(hbuf, g2, be2, r1);

  // 7. FFN1: GELU(xn2 @ W1 + b1) -> f1 (bf16)
  gemm128<2><<<dim3(32, 64), 256, 0, stream>>>(r1, w1_t, b1, nullptr, f1, 4096, 1024);

  // 8. FFN2: f1 @ W2 + b2 + h -> out (fp32)
  gemm128<3><<<dim3(8, 64), 256, 0, stream>>>(f1, w2_t, b2, hbuf, out, 1024, 4096);
}

// Round 3
// 699.841 us; speedup vs baseline: 2.0811x; 1.0690x over previous
//
#include <hip/hip_runtime.h>
#include <hip/hip_bf16.h>

#define EMB 1024
#define SEQ 2048
#define BATCH 4
#define TOK (BATCH*SEQ)
#define NH 16
#define DH 64
#define FF 4096

typedef unsigned short u16;
typedef __bf16 bf16x8 __attribute__((ext_vector_type(8)));
typedef float f32x4 __attribute__((ext_vector_type(4)));

union frag_u { uint4 u4; bf16x8 bf; u16 us[8]; };

__device__ __forceinline__ u16 f2bf(float f) {
  union { float f; unsigned u; } a; a.f = f;
  unsigned r = a.u + 0x7fffu + ((a.u >> 16) & 1u);
  return (u16)(r >> 16);
}

__device__ __forceinline__ void glds16(const void* g, void* l) {
  __builtin_amdgcn_global_load_lds((const __attribute__((address_space(1))) void*)g,
                                   (__attribute__((address_space(3))) void*)l, 16, 0, 0);
}

// ---------------- fp32 [K][N] -> bf16 [N][ldk] transpose+convert ----------------
__global__ __launch_bounds__(256) void cvt_t_kernel(const float* __restrict__ src,
                                                    u16* __restrict__ dst,
                                                    int N, int ldk) {
  __shared__ float tile[32][33];
  int c0 = blockIdx.x * 32, r0 = blockIdx.y * 32;
  int tc = threadIdx.x & 31, tr = threadIdx.x >> 5;  // tr 0..7
  #pragma unroll
  for (int p = 0; p < 4; p++)
    tile[tr + p * 8][tc] = src[(size_t)(r0 + tr + p * 8) * N + c0 + tc];
  __syncthreads();
  #pragma unroll
  for (int p = 0; p < 4; p++)
    dst[(size_t)(c0 + tr + p * 8) * ldk + r0 + tc] = f2bf(tile[tc][tr + p * 8]);
}

// ---------------- LayerNorm (fp32 in -> bf16 out), one wave per row ----------------
__global__ __launch_bounds__(256) void ln_kernel(const float* __restrict__ x,
                                                 const float* __restrict__ g,
                                                 const float* __restrict__ be,
                                                 u16* __restrict__ out) {
  int wave = threadIdx.x >> 6, lane = threadIdx.x & 63;
  int row = blockIdx.x * 4 + wave;
  const float* xr = x + (size_t)row * EMB;
  float4 v[4];
  float s = 0.f;
  #pragma unroll
  for (int i = 0; i < 4; i++) {
    v[i] = *(const float4*)(xr + i * 256 + lane * 4);
    s += v[i].x + v[i].y + v[i].z + v[i].w;
  }
  #pragma unroll
  for (int m = 1; m < 64; m <<= 1) s += __shfl_xor(s, m, 64);
  float mean = s * (1.f / EMB);
  float vs = 0.f;
  #pragma unroll
  for (int i = 0; i < 4; i++) {
    float dx;
    dx = v[i].x - mean; vs += dx * dx;
    dx = v[i].y - mean; vs += dx * dx;
    dx = v[i].z - mean; vs += dx * dx;
    dx = v[i].w - mean; vs += dx * dx;
  }
  #pragma unroll
  for (int m = 1; m < 64; m <<= 1) vs += __shfl_xor(vs, m, 64);
  float inv = rsqrtf(vs * (1.f / EMB) + 1e-5f);
  u16* orow = out + (size_t)row * EMB;
  #pragma unroll
  for (int i = 0; i < 4; i++) {
    int c = i * 256 + lane * 4;
    float4 gv = *(const float4*)(g + c);
    float4 bv = *(const float4*)(be + c);
    ushort4 o;
    o.x = f2bf(gv.x * (v[i].x - mean) * inv + bv.x);
    o.y = f2bf(gv.y * (v[i].y - mean) * inv + bv.y);
    o.z = f2bf(gv.z * (v[i].z - mean) * inv + bv.z);
    o.w = f2bf(gv.w * (v[i].w - mean) * inv + bv.w);
    *(ushort4*)(orow + c) = o;
  }
}

// ---------------- m97-structure 128x128 bf16 MFMA GEMM, B^T input ----------------
template <int MODE>
__global__ __launch_bounds__(256) void gemm128(const u16* __restrict__ A,
                                               const u16* __restrict__ Bt,
                                               const float* __restrict__ bias,
                                               const float* __restrict__ resid,
                                               void* __restrict__ outp,
                                               int N, int K) {
  __shared__ __align__(16) u16 As[128 * 32];
  __shared__ __align__(16) u16 Bs[128 * 32];
  const int t = threadIdx.x;
  const int w = t >> 6, lane = t & 63;
  const int lane15 = lane & 15, quad = lane >> 4;
  const int wr = w >> 1, wc = w & 1;
  const int rowBase = blockIdx.y * 128, colBase = blockIdx.x * 128;

  const int s_row = w * 32 + (lane >> 2);
  const int s_col = (lane & 3) * 8;
  const u16* gA = A + (size_t)(rowBase + s_row) * K + s_col;
  const u16* gB = Bt + (size_t)(colBase + s_row) * K + s_col;
  u16* lA = As + w * 1024;
  u16* lB = Bs + w * 1024;

  f32x4 zero = {0.f, 0.f, 0.f, 0.f};
  f32x4 acc[4][4];
  #pragma unroll
  for (int i = 0; i < 4; i++)
    #pragma unroll
    for (int j = 0; j < 4; j++) acc[i][j] = zero;

  for (int k0 = 0; k0 < K; k0 += 32) {
    __syncthreads();
    glds16(gA + k0, lA);
    glds16(gA + (size_t)16 * K + k0, lA + 512);
    glds16(gB + k0, lB);
    glds16(gB + (size_t)16 * K + k0, lB + 512);
    __syncthreads();
    frag_u a4[4], b4[4];
    #pragma unroll
    for (int mi = 0; mi < 4; mi++)
      a4[mi].u4 = *(const uint4*)(As + (wr * 64 + mi * 16 + lane15) * 32 + quad * 8);
    #pragma unroll
    for (int ni = 0; ni < 4; ni++)
      b4[ni].u4 = *(const uint4*)(Bs + (wc * 64 + ni * 16 + lane15) * 32 + quad * 8);
    #pragma unroll
    for (int mi = 0; mi < 4; mi++)
      #pragma unroll
      for (int ni = 0; ni < 4; ni++)
        acc[mi][ni] = __builtin_amdgcn_mfma_f32_16x16x32_bf16(a4[mi].bf, b4[ni].bf, acc[mi][ni], 0, 0, 0);
  }

  #pragma unroll
  for (int mi = 0; mi < 4; mi++) {
    #pragma unroll
    for (int ni = 0; ni < 4; ni++) {
      #pragma unroll
      for (int r = 0; r < 4; r++) {
        int row = rowBase + wr * 64 + mi * 16 + quad * 4 + r;
        int col = colBase + wc * 64 + ni * 16 + lane15;
        float vv = acc[mi][ni][r];
        if (MODE == 1) {
          int mat = col >> 10, cc = col & 1023;
          int hh = cc >> 6, d = cc & 63;
          int b = row >> 11, s = row & 2047;
          ((u16*)outp)[(size_t)mat * (TOK * EMB) +
                       (((size_t)(b * NH + hh) * SEQ + s) << 6) + d] = f2bf(vv);
        } else if (MODE == 2) {
          vv += bias[col];
          vv = 0.5f * vv * (1.f + erff(vv * 0.70710678118f));
          ((u16*)outp)[(size_t)row * N + col] = f2bf(vv);
        } else {
          vv += bias[col] + resid[(size_t)row * N + col];
          ((float*)outp)[(size_t)row * N + col] = vv;
        }
      }
    }
  }
}

// ---------------- V [bh][s][d] -> Vt [bh][d][s], 64x64 LDS tiles ----------------
__global__ __launch_bounds__(256) void vtrans_kernel(const u16* __restrict__ v,
                                                     u16* __restrict__ vt) {
  __shared__ u16 tile[64 * 72];
  int st = blockIdx.x * 64, bh = blockIdx.y;
  const u16* src = v + (size_t)bh * SEQ * DH;
  u16* dst = vt + (size_t)bh * DH * SEQ;
  int r = threadIdx.x >> 2;
  int c = (threadIdx.x & 3) * 16;
  *(uint4*)(tile + r * 72 + c) = *(const uint4*)(src + (size_t)(st + r) * DH + c);
  *(uint4*)(tile + r * 72 + c + 8) = *(const uint4*)(src + (size_t)(st + r) * DH + c + 8);
  __syncthreads();
  u16 tmp[16];
  #pragma unroll
  for (int j = 0; j < 16; j++) tmp[j] = tile[(c + j) * 72 + r];
  *(uint4*)(dst + (size_t)r * SEQ + st + c) = *(uint4*)tmp;
  *(uint4*)(dst + (size_t)r * SEQ + st + c + 8) = *(uint4*)(tmp + 8);
}

// ---------------- flash attention v2: 128 Q rows/block, no-rescale softmax ----------------
// q,k: [bh][s][d] bf16; vt: [bh][d][s] bf16; ctx: [tok][emb] bf16
__global__ __launch_bounds__(256) void attn_kernel(const u16* __restrict__ q,
                                                   const u16* __restrict__ k,
                                                   const u16* __restrict__ vt,
                                                   u16* __restrict__ ctx) {
  __shared__ __align__(16) u16 Ks[64 * 72];
  __shared__ __align__(16) u16 Vs[64 * 72];
  __shared__ __align__(16) u16 Ps[4 * 32 * 72];
  const int t = threadIdx.x;
  const int w = t >> 6, lane = t & 63;
  const int l15 = lane & 15, quad = lane >> 4;
  const int qt = gridDim.x - 1 - blockIdx.x;   // heavy tiles dispatched first
  const int bh = blockIdx.y;
  const int qBase = qt * 128;
  const size_t kbase = (size_t)bh * SEQ * DH;
  const size_t vtbase = (size_t)bh * DH * SEQ;

  // preload Q fragments (loop-invariant A operands)
  frag_u qf[2][2];
  #pragma unroll
  for (int mi = 0; mi < 2; mi++)
    #pragma unroll
    for (int ks = 0; ks < 2; ks++)
      qf[mi][ks].u4 = *(const uint4*)(q + kbase +
          (size_t)(qBase + w * 32 + mi * 16 + l15) * DH + ks * 32 + quad * 8);

  f32x4 zero = {0.f, 0.f, 0.f, 0.f};
  f32x4 oacc[2][4];
  #pragma unroll
  for (int mi = 0; mi < 2; mi++)
    #pragma unroll
    for (int n0 = 0; n0 < 4; n0++) oacc[mi][n0] = zero;
  float l_r[2][4];
  #pragma unroll
  for (int mi = 0; mi < 2; mi++)
    #pragma unroll
    for (int r = 0; r < 4; r++) l_r[mi][r] = 0.f;

  // staging: 256 threads cover a 64x64 bf16 tile; thread -> row t>>2, col (t&3)*8 (+32)
  const int sr = t >> 2;
  const int scol = (t & 3) * 8;
  const u16* gK = k + kbase + scol;
  const u16* gV = vt + vtbase + (size_t)sr * SEQ + scol;
  u16* sK = Ks + sr * 72 + scol;
  u16* sV = Vs + sr * 72 + scol;
  u16* PsW = Ps + w * 32 * 72;

  const int ktEnd = 2 * qt + 1;
  for (int kt = 0; kt <= ktEnd; kt++) {
    __syncthreads();
    uint4 ka = *(const uint4*)(gK + (size_t)(kt * 64 + sr) * DH);
    uint4 kb = *(const uint4*)(gK + (size_t)(kt * 64 + sr) * DH + 32);
    uint4 va = *(const uint4*)(gV + kt * 64);
    uint4 vb = *(const uint4*)(gV + kt * 64 + 32);
    *(uint4*)sK = ka; *(uint4*)(sK + 32) = kb;
    *(uint4*)sV = va; *(uint4*)(sV + 32) = vb;
    __syncthreads();

    // S = Q K^T  (B-frags from Ks, A-frags preloaded)
    f32x4 sacc[2][4];
    #pragma unroll
    for (int mi = 0; mi < 2; mi++)
      #pragma unroll
      for (int n0 = 0; n0 < 4; n0++) sacc[mi][n0] = zero;
    #pragma unroll
    for (int ks = 0; ks < 2; ks++) {
      #pragma unroll
      for (int n0 = 0; n0 < 4; n0++) {
        frag_u b;
        b.u4 = *(const uint4*)(Ks + (n0 * 16 + l15) * 72 + ks * 32 + quad * 8);
        #pragma unroll
        for (int mi = 0; mi < 2; mi++)
          sacc[mi][n0] = __builtin_amdgcn_mfma_f32_16x16x32_bf16(qf[mi][ks].bf, b.bf, sacc[mi][n0], 0, 0, 0);
      }
    }

    // softmax without running max: P = exp2(S * 0.125*log2e); accumulate l
    const bool diag = (kt >= 2 * qt);
    #pragma unroll
    for (int mi = 0; mi < 2; mi++) {
      #pragma unroll
      for (int r = 0; r < 4; r++) {
        int qrow = qBase + w * 32 + mi * 16 + quad * 4 + r;
        float ps = 0.f;
        #pragma unroll
        for (int n0 = 0; n0 < 4; n0++) {
          float p = exp2f(sacc[mi][n0][r] * 0.1803368801f);
          if (diag && (kt * 64 + n0 * 16 + l15) > qrow) p = 0.f;
          sacc[mi][n0][r] = p;
          ps += p;
        }
        #pragma unroll
        for (int off = 1; off < 16; off <<= 1) ps += __shfl_xor(ps, off, 64);
        l_r[mi][r] += ps;
        #pragma unroll
        for (int n0 = 0; n0 < 4; n0++)
          PsW[(mi * 16 + quad * 4 + r) * 72 + n0 * 16 + l15] = f2bf(sacc[mi][n0][r]);
      }
    }

    // O += P V  (A-frags from PsW, B-frags from Vs = V^T rows)
    #pragma unroll
    for (int ks = 0; ks < 2; ks++) {
      frag_u a[2];
      #pragma unroll
      for (int mi = 0; mi < 2; mi++)
        a[mi].u4 = *(const uint4*)(PsW + (mi * 16 + l15) * 72 + ks * 32 + quad * 8);
      #pragma unroll
      for (int n0 = 0; n0 < 4; n0++) {
        frag_u b;
        b.u4 = *(const uint4*)(Vs + (n0 * 16 + l15) * 72 + ks * 32 + quad * 8);
        #pragma unroll
        for (int mi = 0; mi < 2; mi++)
          oacc[mi][n0] = __builtin_amdgcn_mfma_f32_16x16x32_bf16(a[mi].bf, b.bf, oacc[mi][n0], 0, 0, 0);
      }
    }
  }

  // epilogue
  int bq = bh >> 4, hh = bh & 15;
  float inv_l[2][4];
  #pragma unroll
  for (int mi = 0; mi < 2; mi++)
    #pragma unroll
    for (int r = 0; r < 4; r++) inv_l[mi][r] = 1.f / l_r[mi][r];
  #pragma unroll
  for (int mi = 0; mi < 2; mi++) {
    #pragma unroll
    for (int n0 = 0; n0 < 4; n0++) {
      #pragma unroll
      for (int r = 0; r < 4; r++) {
        int s = qBase + w * 32 + mi * 16 + quad * 4 + r;
        int col = hh * 64 + n0 * 16 + l15;
        ctx[((size_t)(bq * SEQ + s)) * EMB + col] = f2bf(oacc[mi][n0][r] * inv_l[mi][r]);
      }
    }
  }
}

extern "C" void kernel_launch(void* const* d_in, const int* in_sizes, int n_in,
                              void* d_out, int out_size, void* d_ws, size_t ws_size,
                              hipStream_t stream) {
  const float* x  = (const float*)d_in[0];
  const float* Wq = (const float*)d_in[1];
  const float* Wk = (const float*)d_in[2];
  const float* Wv = (const float*)d_in[3];
  const float* Wo = (const float*)d_in[4];
  const float* bo = (const float*)d_in[5];
  const float* W1 = (const float*)d_in[6];
  const float* b1 = (const float*)d_in[7];
  const float* W2 = (const float*)d_in[8];
  const float* b2 = (const float*)d_in[9];
  const float* g1  = (const float*)d_in[10];
  const float* be1 = (const float*)d_in[11];
  const float* g2  = (const float*)d_in[12];
  const float* be2 = (const float*)d_in[13];
  float* out = (float*)d_out;
  char* ws = (char*)d_ws;
  const size_t MB = 1u << 20;

  u16* wqkv_t = (u16*)(ws + 0 * MB);          // 6 MB
  u16* wo_t   = (u16*)(ws + 6 * MB);          // 2 MB
  u16* w1_t   = (u16*)(ws + 8 * MB);          // 8 MB
  u16* w2_t   = (u16*)(ws + 16 * MB);         // 8 MB
  float* hbuf = (float*)(ws + 24 * MB);       // 32 MB fp32 residual h
  u16* r1 = (u16*)(ws + 56 * MB);             // 16 MB: xn1 -> ctx -> xn2
  u16* qb = (u16*)(ws + 72 * MB);             // q,k,v 16 MB each (contiguous for fused store)
  u16* vb = (u16*)(ws + 104 * MB);
  u16* vtb = (u16*)(ws + 120 * MB);           // 16 MB V^T [bh][d][s]
  u16* f1 = (u16*)(ws + 72 * MB);             // 64 MB, overlaps q/k/v/vt (dead after attn)

  cvt_t_kernel<<<dim3(32, 32), 256, 0, stream>>>(Wq, wqkv_t, 1024, 1024);
  cvt_t_kernel<<<dim3(32, 32), 256, 0, stream>>>(Wk, wqkv_t + 1024 * 1024, 1024, 1024);
  cvt_t_kernel<<<dim3(32, 32), 256, 0, stream>>>(Wv, wqkv_t + 2 * 1024 * 1024, 1024, 1024);
  cvt_t_kernel<<<dim3(32, 32), 256, 0, stream>>>(Wo, wo_t, 1024, 1024);
  cvt_t_kernel<<<dim3(128, 32), 256, 0, stream>>>(W1, w1_t, 4096, 1024);
  cvt_t_kernel<<<dim3(32, 128), 256, 0, stream>>>(W2, w2_t, 1024, 4096);

  ln_kernel<<<2048, 256, 0, stream>>>(x, g1, be1, r1);

  gemm128<1><<<dim3(24, 64), 256, 0, stream>>>(r1, wqkv_t, nullptr, nullptr, qb, 3072, 1024);

  vtrans_kernel<<<dim3(32, 64), 256, 0, stream>>>(vb, vtb);

  attn_kernel<<<dim3(16, 64), 256, 0, stream>>>(qb, qb + 16 * 1024 * 1024 / 2, vtb, r1);

  gemm128<3><<<dim3(8, 64), 256, 0, stream>>>(r1, wo_t, bo, x, hbuf, 1024, 1024);

  ln_kernel<<<2048, 256, 0, stream>>>(hbuf, g2, be2, r1);

  gemm128<2><<<dim3(32, 64), 256, 0, stream>>>(r1, w1_t, b1, nullptr, f1, 4096, 1024);

  gemm128<3><<<dim3(8, 64), 256, 0, stream>>>(f1, w2_t, b2, hbuf, out, 1024, 4096);
}

// Round 4
// 571.651 us; speedup vs baseline: 2.5477x; 1.2242x over previous
//
#include <hip/hip_runtime.h>
#include <hip/hip_bf16.h>

#define EMB 1024
#define SEQ 2048
#define BATCH 4
#define TOK (BATCH*SEQ)
#define NH 16
#define DH 64
#define FF 4096

typedef unsigned short u16;
typedef __bf16 bf16x8 __attribute__((ext_vector_type(8)));
typedef float f32x4 __attribute__((ext_vector_type(4)));

union frag_u { uint4 u4; bf16x8 bf; u16 us[8]; };

__device__ __forceinline__ u16 f2bf(float f) {
  union { float f; unsigned u; } a; a.f = f;
  unsigned r = a.u + 0x7fffu + ((a.u >> 16) & 1u);
  return (u16)(r >> 16);
}

__device__ __forceinline__ void glds16(const void* g, void* l) {
  __builtin_amdgcn_global_load_lds((const __attribute__((address_space(1))) void*)g,
                                   (__attribute__((address_space(3))) void*)l, 16, 0, 0);
}

// ---------------- fp32 [K][N] -> bf16 [N][ldk] transpose+convert ----------------
__global__ __launch_bounds__(256) void cvt_t_kernel(const float* __restrict__ src,
                                                    u16* __restrict__ dst,
                                                    int N, int ldk) {
  __shared__ float tile[32][33];
  int c0 = blockIdx.x * 32, r0 = blockIdx.y * 32;
  int tc = threadIdx.x & 31, tr = threadIdx.x >> 5;
  #pragma unroll
  for (int p = 0; p < 4; p++)
    tile[tr + p * 8][tc] = src[(size_t)(r0 + tr + p * 8) * N + c0 + tc];
  __syncthreads();
  #pragma unroll
  for (int p = 0; p < 4; p++)
    dst[(size_t)(c0 + tr + p * 8) * ldk + r0 + tc] = f2bf(tile[tc][tr + p * 8]);
}

// ---------------- LayerNorm (fp32 in -> bf16 out), one wave per row ----------------
__global__ __launch_bounds__(256) void ln_kernel(const float* __restrict__ x,
                                                 const float* __restrict__ g,
                                                 const float* __restrict__ be,
                                                 u16* __restrict__ out) {
  int wave = threadIdx.x >> 6, lane = threadIdx.x & 63;
  int row = blockIdx.x * 4 + wave;
  const float* xr = x + (size_t)row * EMB;
  float4 v[4];
  float s = 0.f;
  #pragma unroll
  for (int i = 0; i < 4; i++) {
    v[i] = *(const float4*)(xr + i * 256 + lane * 4);
    s += v[i].x + v[i].y + v[i].z + v[i].w;
  }
  #pragma unroll
  for (int m = 1; m < 64; m <<= 1) s += __shfl_xor(s, m, 64);
  float mean = s * (1.f / EMB);
  float vs = 0.f;
  #pragma unroll
  for (int i = 0; i < 4; i++) {
    float dx;
    dx = v[i].x - mean; vs += dx * dx;
    dx = v[i].y - mean; vs += dx * dx;
    dx = v[i].z - mean; vs += dx * dx;
    dx = v[i].w - mean; vs += dx * dx;
  }
  #pragma unroll
  for (int m = 1; m < 64; m <<= 1) vs += __shfl_xor(vs, m, 64);
  float inv = rsqrtf(vs * (1.f / EMB) + 1e-5f);
  u16* orow = out + (size_t)row * EMB;
  #pragma unroll
  for (int i = 0; i < 4; i++) {
    int c = i * 256 + lane * 4;
    float4 gv = *(const float4*)(g + c);
    float4 bv = *(const float4*)(be + c);
    ushort4 o;
    o.x = f2bf(gv.x * (v[i].x - mean) * inv + bv.x);
    o.y = f2bf(gv.y * (v[i].y - mean) * inv + bv.y);
    o.z = f2bf(gv.z * (v[i].z - mean) * inv + bv.z);
    o.w = f2bf(gv.w * (v[i].w - mean) * inv + bv.w);
    *(ushort4*)(orow + c) = o;
  }
}

// ---------------- m97-structure 128x128 bf16 MFMA GEMM, B^T input ----------------
// MODE 1: fused-QKV; q,k -> [bh][s][d], v -> [bh][d][s] (transposed, vectorized)
// MODE 2: +bias, exact GELU, bf16 out; MODE 3: +bias +residual, fp32 out.
template <int MODE>
__global__ __launch_bounds__(256) void gemm128(const u16* __restrict__ A,
                                               const u16* __restrict__ Bt,
                                               const float* __restrict__ bias,
                                               const float* __restrict__ resid,
                                               void* __restrict__ outp,
                                               int N, int K) {
  __shared__ __align__(16) u16 As[128 * 32];
  __shared__ __align__(16) u16 Bs[128 * 32];
  const int t = threadIdx.x;
  const int w = t >> 6, lane = t & 63;
  const int lane15 = lane & 15, quad = lane >> 4;
  const int wr = w >> 1, wc = w & 1;
  const int rowBase = blockIdx.y * 128, colBase = blockIdx.x * 128;

  const int s_row = w * 32 + (lane >> 2);
  const int s_col = (lane & 3) * 8;
  const u16* gA = A + (size_t)(rowBase + s_row) * K + s_col;
  const u16* gB = Bt + (size_t)(colBase + s_row) * K + s_col;
  u16* lA = As + w * 1024;
  u16* lB = Bs + w * 1024;

  f32x4 zero = {0.f, 0.f, 0.f, 0.f};
  f32x4 acc[4][4];
  #pragma unroll
  for (int i = 0; i < 4; i++)
    #pragma unroll
    for (int j = 0; j < 4; j++) acc[i][j] = zero;

  for (int k0 = 0; k0 < K; k0 += 32) {
    __syncthreads();
    glds16(gA + k0, lA);
    glds16(gA + (size_t)16 * K + k0, lA + 512);
    glds16(gB + k0, lB);
    glds16(gB + (size_t)16 * K + k0, lB + 512);
    __syncthreads();
    frag_u a4[4], b4[4];
    #pragma unroll
    for (int mi = 0; mi < 4; mi++)
      a4[mi].u4 = *(const uint4*)(As + (wr * 64 + mi * 16 + lane15) * 32 + quad * 8);
    #pragma unroll
    for (int ni = 0; ni < 4; ni++)
      b4[ni].u4 = *(const uint4*)(Bs + (wc * 64 + ni * 16 + lane15) * 32 + quad * 8);
    #pragma unroll
    for (int mi = 0; mi < 4; mi++)
      #pragma unroll
      for (int ni = 0; ni < 4; ni++)
        acc[mi][ni] = __builtin_amdgcn_mfma_f32_16x16x32_bf16(a4[mi].bf, b4[ni].bf, acc[mi][ni], 0, 0, 0);
  }

  #pragma unroll
  for (int mi = 0; mi < 4; mi++) {
    #pragma unroll
    for (int ni = 0; ni < 4; ni++) {
      int col = colBase + wc * 64 + ni * 16 + lane15;
      int row0 = rowBase + wr * 64 + mi * 16 + quad * 4;
      if (MODE == 1) {
        int mat = col >> 10, cc = col & 1023;
        int hh = cc >> 6, d = cc & 63;
        int b = row0 >> 11, s0 = row0 & 2047;
        if (mat == 2) {
          // V^T store: [bh][d][s], 4 consecutive s per lane -> one 8B store
          uint2 pk;
          pk.x = (unsigned)f2bf(acc[mi][ni][0]) | ((unsigned)f2bf(acc[mi][ni][1]) << 16);
          pk.y = (unsigned)f2bf(acc[mi][ni][2]) | ((unsigned)f2bf(acc[mi][ni][3]) << 16);
          *(uint2*)((u16*)outp + 2 * (size_t)TOK * EMB +
                    ((size_t)((b * NH + hh) * DH + d)) * SEQ + s0) = pk;
        } else {
          #pragma unroll
          for (int r = 0; r < 4; r++)
            ((u16*)outp)[(size_t)mat * (TOK * EMB) +
                         (((size_t)(b * NH + hh) * SEQ + s0 + r) << 6) + d] = f2bf(acc[mi][ni][r]);
        }
      } else {
        #pragma unroll
        for (int r = 0; r < 4; r++) {
          int row = row0 + r;
          float vv = acc[mi][ni][r];
          if (MODE == 2) {
            vv += bias[col];
            vv = 0.5f * vv * (1.f + erff(vv * 0.70710678118f));
            ((u16*)outp)[(size_t)row * N + col] = f2bf(vv);
          } else {
            vv += bias[col] + resid[(size_t)row * N + col];
            ((float*)outp)[(size_t)row * N + col] = vv;
          }
        }
      }
    }
  }
}

// ---------------- flash attention v3: S^T formulation, paired q-tiles ----------------
// q,k: [bh][s][d]; vt: [bh][d][s]; ctx: [tok][emb]. Grid (bh=64, pair=8).
__global__ __launch_bounds__(256) void attn_kernel(const u16* __restrict__ q,
                                                   const u16* __restrict__ k,
                                                   const u16* __restrict__ vt,
                                                   u16* __restrict__ ctx) {
  __shared__ __align__(16) u16 Ks[64 * 72];
  __shared__ __align__(16) u16 Vs[64 * 72];
  __shared__ __align__(16) u16 Ps[128 * 72];
  __shared__ float Ls[128];
  const int t = threadIdx.x;
  const int w = t >> 6, lane = t & 63;
  const int l15 = lane & 15, quad = lane >> 4;
  const int bh = blockIdx.x, pr_ = blockIdx.y;
  const size_t base = (size_t)bh * SEQ * DH;
  const int bq = bh >> 4, hh = bh & 15;

  const int sr = t >> 2, scol = (t & 3) * 8;
  const u16* gK = k + base + (size_t)sr * DH + scol;
  const u16* gV = vt + base + (size_t)sr * SEQ + scol;
  u16* sK = Ks + sr * 72 + scol;
  u16* sV = Vs + sr * 72 + scol;

  f32x4 zero = {0.f, 0.f, 0.f, 0.f};
  uint4 rK0, rK1, rV0, rV1;
  rK0 = *(const uint4*)(gK);
  rK1 = *(const uint4*)(gK + 32);
  rV0 = *(const uint4*)(gV);
  rV1 = *(const uint4*)(gV + 32);

  for (int ti = 0; ti < 2; ti++) {
    const int qt = ti ? (15 - pr_) : pr_;
    const int qBase = qt * 128;
    const int ktEnd = 2 * qt + 1;

    frag_u qf[2][2];
    #pragma unroll
    for (int ni = 0; ni < 2; ni++)
      #pragma unroll
      for (int ks = 0; ks < 2; ks++)
        qf[ni][ks].u4 = *(const uint4*)(q + base +
            (size_t)(qBase + w * 32 + ni * 16 + l15) * DH + ks * 32 + quad * 8);

    f32x4 oacc[2][4];
    #pragma unroll
    for (int mi = 0; mi < 2; mi++)
      #pragma unroll
      for (int n0 = 0; n0 < 4; n0++) oacc[mi][n0] = zero;
    float l0 = 0.f, l1 = 0.f;

    for (int kt = 0; kt <= ktEnd; kt++) {
      __syncthreads();
      *(uint4*)sK = rK0; *(uint4*)(sK + 32) = rK1;
      *(uint4*)sV = rV0; *(uint4*)(sV + 32) = rV1;
      __syncthreads();
      int nkt = (kt < ktEnd) ? kt + 1 : (ti == 0 ? 0 : -1);
      if (nkt >= 0) {
        rK0 = *(const uint4*)(gK + (size_t)(nkt * 64) * DH);
        rK1 = *(const uint4*)(gK + (size_t)(nkt * 64) * DH + 32);
        rV0 = *(const uint4*)(gV + nkt * 64);
        rV1 = *(const uint4*)(gV + nkt * 64 + 32);
      }
      const int rel = kt - 2 * qt;
      if (rel == 1 && w < 2) continue;   // whole sub-tile masked for waves 0,1

      // S^T = K Q^T : A = K rows (keys), B = Q rows (queries)
      frag_u kf[4][2];
      #pragma unroll
      for (int mi = 0; mi < 4; mi++)
        #pragma unroll
        for (int ks = 0; ks < 2; ks++)
          kf[mi][ks].u4 = *(const uint4*)(Ks + (mi * 16 + l15) * 72 + ks * 32 + quad * 8);
      f32x4 st[4][2];
      #pragma unroll
      for (int mi = 0; mi < 4; mi++)
        #pragma unroll
        for (int ni = 0; ni < 2; ni++) st[mi][ni] = zero;
      #pragma unroll
      for (int ks = 0; ks < 2; ks++)
        #pragma unroll
        for (int mi = 0; mi < 4; mi++)
          #pragma unroll
          for (int ni = 0; ni < 2; ni++)
            st[mi][ni] = __builtin_amdgcn_mfma_f32_16x16x32_bf16(kf[mi][ks].bf, qf[ni][ks].bf, st[mi][ni], 0, 0, 0);

      const bool doMask = (rel == 0 && w < 2) || (rel == 1);
      #pragma unroll
      for (int ni = 0; ni < 2; ni++) {
        const int qrow = qBase + w * 32 + ni * 16 + l15;
        float sum = 0.f;
        u16* prow = Ps + (w * 32 + ni * 16 + l15) * 72;
        #pragma unroll
        for (int mi = 0; mi < 4; mi++) {
          float p[4];
          #pragma unroll
          for (int r = 0; r < 4; r++) {
            p[r] = __expf(st[mi][ni][r] * 0.125f);
            if (doMask && (kt * 64 + mi * 16 + quad * 4 + r) > qrow) p[r] = 0.f;
            sum += p[r];
          }
          uint2 pk;
          pk.x = (unsigned)f2bf(p[0]) | ((unsigned)f2bf(p[1]) << 16);
          pk.y = (unsigned)f2bf(p[2]) | ((unsigned)f2bf(p[3]) << 16);
          *(uint2*)(prow + mi * 16 + quad * 4) = pk;
        }
        sum += __shfl_xor(sum, 16, 64);
        sum += __shfl_xor(sum, 32, 64);
        if (ni == 0) l0 += sum; else l1 += sum;
      }

      // O += P V  (A = P rows from Ps, B = V^T rows from Vs)
      frag_u pa[2][2];
      #pragma unroll
      for (int mi = 0; mi < 2; mi++)
        #pragma unroll
        for (int ks = 0; ks < 2; ks++)
          pa[mi][ks].u4 = *(const uint4*)(Ps + (w * 32 + mi * 16 + l15) * 72 + ks * 32 + quad * 8);
      #pragma unroll
      for (int ks = 0; ks < 2; ks++)
        #pragma unroll
        for (int n0 = 0; n0 < 4; n0++) {
          frag_u b;
          b.u4 = *(const uint4*)(Vs + (n0 * 16 + l15) * 72 + ks * 32 + quad * 8);
          #pragma unroll
          for (int mi = 0; mi < 2; mi++)
            oacc[mi][n0] = __builtin_amdgcn_mfma_f32_16x16x32_bf16(pa[mi][ks].bf, b.bf, oacc[mi][n0], 0, 0, 0);
        }
    }

    // epilogue for this tile
    if (quad == 0) {
      Ls[w * 32 + l15] = l0;
      Ls[w * 32 + 16 + l15] = l1;
    }
    #pragma unroll
    for (int mi = 0; mi < 2; mi++) {
      float il[4];
      #pragma unroll
      for (int r = 0; r < 4; r++) il[r] = 1.f / Ls[w * 32 + mi * 16 + quad * 4 + r];
      #pragma unroll
      for (int n0 = 0; n0 < 4; n0++) {
        int s = qBase + w * 32 + mi * 16 + quad * 4;
        int col = hh * 64 + n0 * 16 + l15;
        #pragma unroll
        for (int r = 0; r < 4; r++)
          ctx[((size_t)(bq * SEQ + s + r)) * EMB + col] = f2bf(oacc[mi][n0][r] * il[r]);
      }
    }
  }
}

extern "C" void kernel_launch(void* const* d_in, const int* in_sizes, int n_in,
                              void* d_out, int out_size, void* d_ws, size_t ws_size,
                              hipStream_t stream) {
  const float* x  = (const float*)d_in[0];
  const float* Wq = (const float*)d_in[1];
  const float* Wk = (const float*)d_in[2];
  const float* Wv = (const float*)d_in[3];
  const float* Wo = (const float*)d_in[4];
  const float* bo = (const float*)d_in[5];
  const float* W1 = (const float*)d_in[6];
  const float* b1 = (const float*)d_in[7];
  const float* W2 = (const float*)d_in[8];
  const float* b2 = (const float*)d_in[9];
  const float* g1  = (const float*)d_in[10];
  const float* be1 = (const float*)d_in[11];
  const float* g2  = (const float*)d_in[12];
  const float* be2 = (const float*)d_in[13];
  float* out = (float*)d_out;
  char* ws = (char*)d_ws;
  const size_t MB = 1u << 20;

  u16* wqkv_t = (u16*)(ws + 0 * MB);          // 6 MB
  u16* wo_t   = (u16*)(ws + 6 * MB);          // 2 MB
  u16* w1_t   = (u16*)(ws + 8 * MB);          // 8 MB
  u16* w2_t   = (u16*)(ws + 16 * MB);         // 8 MB
  float* hbuf = (float*)(ws + 24 * MB);       // 32 MB fp32 residual h
  u16* r1 = (u16*)(ws + 56 * MB);             // 16 MB: xn1 -> ctx -> xn2
  u16* qb = (u16*)(ws + 72 * MB);             // q,k 16 MB each; vt 16 MB [bh][d][s]
  u16* f1 = (u16*)(ws + 72 * MB);             // 64 MB, overlaps q/k/vt (dead after attn)

  cvt_t_kernel<<<dim3(32, 32), 256, 0, stream>>>(Wq, wqkv_t, 1024, 1024);
  cvt_t_kernel<<<dim3(32, 32), 256, 0, stream>>>(Wk, wqkv_t + 1024 * 1024, 1024, 1024);
  cvt_t_kernel<<<dim3(32, 32), 256, 0, stream>>>(Wv, wqkv_t + 2 * 1024 * 1024, 1024, 1024);
  cvt_t_kernel<<<dim3(32, 32), 256, 0, stream>>>(Wo, wo_t, 1024, 1024);
  cvt_t_kernel<<<dim3(128, 32), 256, 0, stream>>>(W1, w1_t, 4096, 1024);
  cvt_t_kernel<<<dim3(32, 128), 256, 0, stream>>>(W2, w2_t, 1024, 4096);

  ln_kernel<<<2048, 256, 0, stream>>>(x, g1, be1, r1);

  // fused QKV projection; q,k row-major, v transposed to [bh][d][s]
  gemm128<1><<<dim3(24, 64), 256, 0, stream>>>(r1, wqkv_t, nullptr, nullptr, qb, 3072, 1024);

  attn_kernel<<<dim3(64, 8), 256, 0, stream>>>(qb, qb + (size_t)TOK * EMB,
                                               qb + 2 * (size_t)TOK * EMB, r1);

  gemm128<3><<<dim3(8, 64), 256, 0, stream>>>(r1, wo_t, bo, x, hbuf, 1024, 1024);

  ln_kernel<<<2048, 256, 0, stream>>>(hbuf, g2, be2, r1);

  gemm128<2><<<dim3(32, 64), 256, 0, stream>>>(r1, w1_t, b1, nullptr, f1, 4096, 1024);

  gemm128<3><<<dim3(8, 64), 256, 0, stream>>>(f1, w2_t, b2, hbuf, out, 1024, 4096);
}

// Round 5
// 529.916 us; speedup vs baseline: 2.7484x; 1.0788x over previous
//
#include <hip/hip_runtime.h>
#include <hip/hip_bf16.h>

#define EMB 1024
#define SEQ 2048
#define BATCH 4
#define TOK (BATCH*SEQ)
#define NH 16
#define DH 64
#define FF 4096

typedef unsigned short u16;
typedef __bf16 bf16x8 __attribute__((ext_vector_type(8)));
typedef float f32x4 __attribute__((ext_vector_type(4)));

union frag_u { uint4 u4; bf16x8 bf; u16 us[8]; };

__device__ __forceinline__ u16 f2bf(float f) {
  union { float f; unsigned u; } a; a.f = f;
  unsigned r = a.u + 0x7fffu + ((a.u >> 16) & 1u);
  return (u16)(r >> 16);
}

__device__ __forceinline__ void glds16(const void* g, void* l) {
  __builtin_amdgcn_global_load_lds((const __attribute__((address_space(1))) void*)g,
                                   (__attribute__((address_space(3))) void*)l, 16, 0, 0);
}

// fast exact-enough GELU (tanh form, max abs err ~3e-4)
__device__ __forceinline__ float gelu_fast(float u) {
  float u2 = u * u;
  float c = fmaf(u2, 0.0356774081f, 0.7978845608f);
  float e = __expf(2.f * u * c);
  return u * e * __builtin_amdgcn_rcpf(e + 1.f);
}

// ---------------- fp32 [K][N] -> bf16 [N][ldk] transpose+convert ----------------
__global__ __launch_bounds__(256) void cvt_t_kernel(const float* __restrict__ src,
                                                    u16* __restrict__ dst,
                                                    int N, int ldk) {
  __shared__ float tile[32][33];
  int c0 = blockIdx.x * 32, r0 = blockIdx.y * 32;
  int tc = threadIdx.x & 31, tr = threadIdx.x >> 5;
  #pragma unroll
  for (int p = 0; p < 4; p++)
    tile[tr + p * 8][tc] = src[(size_t)(r0 + tr + p * 8) * N + c0 + tc];
  __syncthreads();
  #pragma unroll
  for (int p = 0; p < 4; p++)
    dst[(size_t)(c0 + tr + p * 8) * ldk + r0 + tc] = f2bf(tile[tc][tr + p * 8]);
}

// ---------------- LayerNorm (fp32 in -> bf16 out), one wave per row ----------------
__global__ __launch_bounds__(256) void ln_kernel(const float* __restrict__ x,
                                                 const float* __restrict__ g,
                                                 const float* __restrict__ be,
                                                 u16* __restrict__ out) {
  int wave = threadIdx.x >> 6, lane = threadIdx.x & 63;
  int row = blockIdx.x * 4 + wave;
  const float* xr = x + (size_t)row * EMB;
  float4 v[4];
  float s = 0.f;
  #pragma unroll
  for (int i = 0; i < 4; i++) {
    v[i] = *(const float4*)(xr + i * 256 + lane * 4);
    s += v[i].x + v[i].y + v[i].z + v[i].w;
  }
  #pragma unroll
  for (int m = 1; m < 64; m <<= 1) s += __shfl_xor(s, m, 64);
  float mean = s * (1.f / EMB);
  float vs = 0.f;
  #pragma unroll
  for (int i = 0; i < 4; i++) {
    float dx;
    dx = v[i].x - mean; vs += dx * dx;
    dx = v[i].y - mean; vs += dx * dx;
    dx = v[i].z - mean; vs += dx * dx;
    dx = v[i].w - mean; vs += dx * dx;
  }
  #pragma unroll
  for (int m = 1; m < 64; m <<= 1) vs += __shfl_xor(vs, m, 64);
  float inv = rsqrtf(vs * (1.f / EMB) + 1e-5f);
  u16* orow = out + (size_t)row * EMB;
  #pragma unroll
  for (int i = 0; i < 4; i++) {
    int c = i * 256 + lane * 4;
    float4 gv = *(const float4*)(g + c);
    float4 bv = *(const float4*)(be + c);
    ushort4 o;
    o.x = f2bf(gv.x * (v[i].x - mean) * inv + bv.x);
    o.y = f2bf(gv.y * (v[i].y - mean) * inv + bv.y);
    o.z = f2bf(gv.z * (v[i].z - mean) * inv + bv.z);
    o.w = f2bf(gv.w * (v[i].w - mean) * inv + bv.w);
    *(ushort4*)(orow + c) = o;
  }
}

// ---------------- 128x128 bf16 MFMA GEMM, BK=64, XOR-swizzled LDS ----------------
// A: [M][K], Bt: [N][K]. MODE 1: fused-QKV (q,k row-major, v transposed);
// MODE 2: +bias fast-GELU bf16 out; MODE 3: +bias +residual fp32 out.
template <int MODE>
__global__ __launch_bounds__(256) void gemm128(const u16* __restrict__ A,
                                               const u16* __restrict__ Bt,
                                               const float* __restrict__ bias,
                                               const float* __restrict__ resid,
                                               void* __restrict__ outp,
                                               int N, int K) {
  __shared__ __align__(16) u16 As[128 * 64];
  __shared__ __align__(16) u16 Bs[128 * 64];
  const int t = threadIdx.x;
  const int w = t >> 6, lane = t & 63;
  const int l15 = lane & 15, quad = lane >> 4;
  const int wr = w >> 1, wc = w & 1;
  const int rowBase = blockIdx.y * 128, colBase = blockIdx.x * 128;

  // staging: wave w, issue j covers rows w*8 + j*32 .. +8; 8 lanes/row,
  // lane loads global k-chunk ((lane&7) ^ row) so LDS slot c holds chunk c^row&7
  const int sr = lane >> 3;
  const int sc = ((lane & 7) ^ sr) * 8;
  const u16* gA = A + (size_t)(rowBase + w * 8 + sr) * K + sc;
  const u16* gB = Bt + (size_t)(colBase + w * 8 + sr) * K + sc;
  u16* lA = As + w * 8 * 64;
  u16* lB = Bs + w * 8 * 64;

  const int swz0 = (quad ^ (l15 & 7)) * 8;         // kk=0 chunk byte-offset/2
  const int swz1 = ((quad + 4) ^ (l15 & 7)) * 8;   // kk=1

  f32x4 zero = {0.f, 0.f, 0.f, 0.f};
  f32x4 acc[4][4];
  #pragma unroll
  for (int i = 0; i < 4; i++)
    #pragma unroll
    for (int j = 0; j < 4; j++) acc[i][j] = zero;

  for (int k0 = 0; k0 < K; k0 += 64) {
    __syncthreads();
    #pragma unroll
    for (int j = 0; j < 4; j++) {
      glds16(gA + (size_t)(j * 32) * K + k0, lA + j * 32 * 64);
      glds16(gB + (size_t)(j * 32) * K + k0, lB + j * 32 * 64);
    }
    __syncthreads();
    #pragma unroll
    for (int kk = 0; kk < 2; kk++) {
      const int so = kk ? swz1 : swz0;
      frag_u a4[4], b4[4];
      #pragma unroll
      for (int mi = 0; mi < 4; mi++)
        a4[mi].u4 = *(const uint4*)(As + (wr * 64 + mi * 16 + l15) * 64 + so);
      #pragma unroll
      for (int ni = 0; ni < 4; ni++)
        b4[ni].u4 = *(const uint4*)(Bs + (wc * 64 + ni * 16 + l15) * 64 + so);
      #pragma unroll
      for (int mi = 0; mi < 4; mi++)
        #pragma unroll
        for (int ni = 0; ni < 4; ni++)
          acc[mi][ni] = __builtin_amdgcn_mfma_f32_16x16x32_bf16(a4[mi].bf, b4[ni].bf, acc[mi][ni], 0, 0, 0);
    }
  }

  #pragma unroll
  for (int mi = 0; mi < 4; mi++) {
    #pragma unroll
    for (int ni = 0; ni < 4; ni++) {
      int col = colBase + wc * 64 + ni * 16 + l15;
      int row0 = rowBase + wr * 64 + mi * 16 + quad * 4;
      if (MODE == 1) {
        int mat = col >> 10, cc = col & 1023;
        int hh = cc >> 6, d = cc & 63;
        int b = row0 >> 11, s0 = row0 & 2047;
        if (mat == 2) {
          uint2 pk;
          pk.x = (unsigned)f2bf(acc[mi][ni][0]) | ((unsigned)f2bf(acc[mi][ni][1]) << 16);
          pk.y = (unsigned)f2bf(acc[mi][ni][2]) | ((unsigned)f2bf(acc[mi][ni][3]) << 16);
          *(uint2*)((u16*)outp + 2 * (size_t)TOK * EMB +
                    ((size_t)((b * NH + hh) * DH + d)) * SEQ + s0) = pk;
        } else {
          #pragma unroll
          for (int r = 0; r < 4; r++)
            ((u16*)outp)[(size_t)mat * (TOK * EMB) +
                         (((size_t)(b * NH + hh) * SEQ + s0 + r) << 6) + d] = f2bf(acc[mi][ni][r]);
        }
      } else {
        #pragma unroll
        for (int r = 0; r < 4; r++) {
          int row = row0 + r;
          float vv = acc[mi][ni][r];
          if (MODE == 2) {
            vv = gelu_fast(vv + bias[col]);
            ((u16*)outp)[(size_t)row * N + col] = f2bf(vv);
          } else {
            vv += bias[col] + resid[(size_t)row * N + col];
            ((float*)outp)[(size_t)row * N + col] = vv;
          }
        }
      }
    }
  }
}

// ---------------- flash attention v3: S^T formulation, paired q-tiles ----------------
__global__ __launch_bounds__(256) void attn_kernel(const u16* __restrict__ q,
                                                   const u16* __restrict__ k,
                                                   const u16* __restrict__ vt,
                                                   u16* __restrict__ ctx) {
  __shared__ __align__(16) u16 Ks[64 * 72];
  __shared__ __align__(16) u16 Vs[64 * 72];
  __shared__ __align__(16) u16 Ps[128 * 72];
  __shared__ float Ls[128];
  const int t = threadIdx.x;
  const int w = t >> 6, lane = t & 63;
  const int l15 = lane & 15, quad = lane >> 4;
  const int bh = blockIdx.x, pr_ = blockIdx.y;
  const size_t base = (size_t)bh * SEQ * DH;
  const int bq = bh >> 4, hh = bh & 15;

  const int sr = t >> 2, scol = (t & 3) * 8;
  const u16* gK = k + base + (size_t)sr * DH + scol;
  const u16* gV = vt + base + (size_t)sr * SEQ + scol;
  u16* sK = Ks + sr * 72 + scol;
  u16* sV = Vs + sr * 72 + scol;

  f32x4 zero = {0.f, 0.f, 0.f, 0.f};
  uint4 rK0, rK1, rV0, rV1;
  rK0 = *(const uint4*)(gK);
  rK1 = *(const uint4*)(gK + 32);
  rV0 = *(const uint4*)(gV);
  rV1 = *(const uint4*)(gV + 32);

  for (int ti = 0; ti < 2; ti++) {
    const int qt = ti ? (15 - pr_) : pr_;
    const int qBase = qt * 128;
    const int ktEnd = 2 * qt + 1;

    frag_u qf[2][2];
    #pragma unroll
    for (int ni = 0; ni < 2; ni++)
      #pragma unroll
      for (int ks = 0; ks < 2; ks++)
        qf[ni][ks].u4 = *(const uint4*)(q + base +
            (size_t)(qBase + w * 32 + ni * 16 + l15) * DH + ks * 32 + quad * 8);

    f32x4 oacc[2][4];
    #pragma unroll
    for (int mi = 0; mi < 2; mi++)
      #pragma unroll
      for (int n0 = 0; n0 < 4; n0++) oacc[mi][n0] = zero;
    float l0 = 0.f, l1 = 0.f;

    for (int kt = 0; kt <= ktEnd; kt++) {
      __syncthreads();
      *(uint4*)sK = rK0; *(uint4*)(sK + 32) = rK1;
      *(uint4*)sV = rV0; *(uint4*)(sV + 32) = rV1;
      __syncthreads();
      int nkt = (kt < ktEnd) ? kt + 1 : (ti == 0 ? 0 : -1);
      if (nkt >= 0) {
        rK0 = *(const uint4*)(gK + (size_t)(nkt * 64) * DH);
        rK1 = *(const uint4*)(gK + (size_t)(nkt * 64) * DH + 32);
        rV0 = *(const uint4*)(gV + nkt * 64);
        rV1 = *(const uint4*)(gV + nkt * 64 + 32);
      }
      const int rel = kt - 2 * qt;
      if (rel == 1 && w < 2) continue;

      frag_u kf[4][2];
      #pragma unroll
      for (int mi = 0; mi < 4; mi++)
        #pragma unroll
        for (int ks = 0; ks < 2; ks++)
          kf[mi][ks].u4 = *(const uint4*)(Ks + (mi * 16 + l15) * 72 + ks * 32 + quad * 8);
      f32x4 st[4][2];
      #pragma unroll
      for (int mi = 0; mi < 4; mi++)
        #pragma unroll
        for (int ni = 0; ni < 2; ni++) st[mi][ni] = zero;
      #pragma unroll
      for (int ks = 0; ks < 2; ks++)
        #pragma unroll
        for (int mi = 0; mi < 4; mi++)
          #pragma unroll
          for (int ni = 0; ni < 2; ni++)
            st[mi][ni] = __builtin_amdgcn_mfma_f32_16x16x32_bf16(kf[mi][ks].bf, qf[ni][ks].bf, st[mi][ni], 0, 0, 0);

      const bool doMask = (rel == 0 && w < 2) || (rel == 1);
      #pragma unroll
      for (int ni = 0; ni < 2; ni++) {
        const int qrow = qBase + w * 32 + ni * 16 + l15;
        float sum = 0.f;
        u16* prow = Ps + (w * 32 + ni * 16 + l15) * 72;
        #pragma unroll
        for (int mi = 0; mi < 4; mi++) {
          float p[4];
          #pragma unroll
          for (int r = 0; r < 4; r++) {
            p[r] = __expf(st[mi][ni][r] * 0.125f);
            if (doMask && (kt * 64 + mi * 16 + quad * 4 + r) > qrow) p[r] = 0.f;
            sum += p[r];
          }
          uint2 pk;
          pk.x = (unsigned)f2bf(p[0]) | ((unsigned)f2bf(p[1]) << 16);
          pk.y = (unsigned)f2bf(p[2]) | ((unsigned)f2bf(p[3]) << 16);
          *(uint2*)(prow + mi * 16 + quad * 4) = pk;
        }
        sum += __shfl_xor(sum, 16, 64);
        sum += __shfl_xor(sum, 32, 64);
        if (ni == 0) l0 += sum; else l1 += sum;
      }

      frag_u pa[2][2];
      #pragma unroll
      for (int mi = 0; mi < 2; mi++)
        #pragma unroll
        for (int ks = 0; ks < 2; ks++)
          pa[mi][ks].u4 = *(const uint4*)(Ps + (w * 32 + mi * 16 + l15) * 72 + ks * 32 + quad * 8);
      #pragma unroll
      for (int ks = 0; ks < 2; ks++)
        #pragma unroll
        for (int n0 = 0; n0 < 4; n0++) {
          frag_u b;
          b.u4 = *(const uint4*)(Vs + (n0 * 16 + l15) * 72 + ks * 32 + quad * 8);
          #pragma unroll
          for (int mi = 0; mi < 2; mi++)
            oacc[mi][n0] = __builtin_amdgcn_mfma_f32_16x16x32_bf16(pa[mi][ks].bf, b.bf, oacc[mi][n0], 0, 0, 0);
        }
    }

    if (quad == 0) {
      Ls[w * 32 + l15] = l0;
      Ls[w * 32 + 16 + l15] = l1;
    }
    #pragma unroll
    for (int mi = 0; mi < 2; mi++) {
      float il[4];
      #pragma unroll
      for (int r = 0; r < 4; r++) il[r] = 1.f / Ls[w * 32 + mi * 16 + quad * 4 + r];
      #pragma unroll
      for (int n0 = 0; n0 < 4; n0++) {
        int s = qBase + w * 32 + mi * 16 + quad * 4;
        int col = hh * 64 + n0 * 16 + l15;
        #pragma unroll
        for (int r = 0; r < 4; r++)
          ctx[((size_t)(bq * SEQ + s + r)) * EMB + col] = f2bf(oacc[mi][n0][r] * il[r]);
      }
    }
  }
}

extern "C" void kernel_launch(void* const* d_in, const int* in_sizes, int n_in,
                              void* d_out, int out_size, void* d_ws, size_t ws_size,
                              hipStream_t stream) {
  const float* x  = (const float*)d_in[0];
  const float* Wq = (const float*)d_in[1];
  const float* Wk = (const float*)d_in[2];
  const float* Wv = (const float*)d_in[3];
  const float* Wo = (const float*)d_in[4];
  const float* bo = (const float*)d_in[5];
  const float* W1 = (const float*)d_in[6];
  const float* b1 = (const float*)d_in[7];
  const float* W2 = (const float*)d_in[8];
  const float* b2 = (const float*)d_in[9];
  const float* g1  = (const float*)d_in[10];
  const float* be1 = (const float*)d_in[11];
  const float* g2  = (const float*)d_in[12];
  const float* be2 = (const float*)d_in[13];
  float* out = (float*)d_out;
  char* ws = (char*)d_ws;
  const size_t MB = 1u << 20;

  u16* wqkv_t = (u16*)(ws + 0 * MB);          // 6 MB
  u16* wo_t   = (u16*)(ws + 6 * MB);          // 2 MB
  u16* w1_t   = (u16*)(ws + 8 * MB);          // 8 MB
  u16* w2_t   = (u16*)(ws + 16 * MB);         // 8 MB
  float* hbuf = (float*)(ws + 24 * MB);       // 32 MB fp32 residual h
  u16* r1 = (u16*)(ws + 56 * MB);             // 16 MB: xn1 -> ctx -> xn2
  u16* qb = (u16*)(ws + 72 * MB);             // q,k 16 MB each; vt 16 MB [bh][d][s]
  u16* f1 = (u16*)(ws + 72 * MB);             // 64 MB, overlaps q/k/vt (dead after attn)

  cvt_t_kernel<<<dim3(32, 32), 256, 0, stream>>>(Wq, wqkv_t, 1024, 1024);
  cvt_t_kernel<<<dim3(32, 32), 256, 0, stream>>>(Wk, wqkv_t + 1024 * 1024, 1024, 1024);
  cvt_t_kernel<<<dim3(32, 32), 256, 0, stream>>>(Wv, wqkv_t + 2 * 1024 * 1024, 1024, 1024);
  cvt_t_kernel<<<dim3(32, 32), 256, 0, stream>>>(Wo, wo_t, 1024, 1024);
  cvt_t_kernel<<<dim3(128, 32), 256, 0, stream>>>(W1, w1_t, 4096, 1024);
  cvt_t_kernel<<<dim3(32, 128), 256, 0, stream>>>(W2, w2_t, 1024, 4096);

  ln_kernel<<<2048, 256, 0, stream>>>(x, g1, be1, r1);

  gemm128<1><<<dim3(24, 64), 256, 0, stream>>>(r1, wqkv_t, nullptr, nullptr, qb, 3072, 1024);

  attn_kernel<<<dim3(64, 8), 256, 0, stream>>>(qb, qb + (size_t)TOK * EMB,
                                               qb + 2 * (size_t)TOK * EMB, r1);

  gemm128<3><<<dim3(8, 64), 256, 0, stream>>>(r1, wo_t, bo, x, hbuf, 1024, 1024);

  ln_kernel<<<2048, 256, 0, stream>>>(hbuf, g2, be2, r1);

  gemm128<2><<<dim3(32, 64), 256, 0, stream>>>(r1, w1_t, b1, nullptr, f1, 4096, 1024);

  gemm128<3><<<dim3(8, 64), 256, 0, stream>>>(f1, w2_t, b2, hbuf, out, 1024, 4096);
}

// Round 6
// 504.228 us; speedup vs baseline: 2.8884x; 1.0509x over previous
//
#include <hip/hip_runtime.h>
#include <hip/hip_bf16.h>

#define EMB 1024
#define SEQ 2048
#define BATCH 4
#define TOK (BATCH*SEQ)
#define NH 16
#define DH 64
#define FF 4096

typedef unsigned short u16;
typedef __bf16 bf16x8 __attribute__((ext_vector_type(8)));
typedef float f32x4 __attribute__((ext_vector_type(4)));

union frag_u { uint4 u4; bf16x8 bf; u16 us[8]; };

__device__ __forceinline__ u16 f2bf(float f) {
  union { float f; unsigned u; } a; a.f = f;
  unsigned r = a.u + 0x7fffu + ((a.u >> 16) & 1u);
  return (u16)(r >> 16);
}
__device__ __forceinline__ float bf2f(u16 u) {
  union { unsigned u; float f; } a; a.u = ((unsigned)u) << 16; return a.f;
}

__device__ __forceinline__ void glds16(const void* g, void* l) {
  __builtin_amdgcn_global_load_lds((const __attribute__((address_space(1))) void*)g,
                                   (__attribute__((address_space(3))) void*)l, 16, 0, 0);
}

// fast exact-enough GELU (tanh form, max abs err ~3e-4)
__device__ __forceinline__ float gelu_fast(float u) {
  float u2 = u * u;
  float c = fmaf(u2, 0.0356774081f, 0.7978845608f);
  float e = __expf(2.f * u * c);
  return u * e * __builtin_amdgcn_rcpf(e + 1.f);
}

// ---------------- transpose+convert body: fp32 [K][N] -> bf16 [N][ldk] ----------------
__device__ __forceinline__ void cvt_t_body(const float* __restrict__ src,
                                           u16* __restrict__ dst,
                                           int N, int ldk, int bx, int by) {
  __shared__ float tile[32][33];
  int c0 = bx * 32, r0 = by * 32;
  int tc = threadIdx.x & 31, tr = threadIdx.x >> 5;
  #pragma unroll
  for (int p = 0; p < 4; p++)
    tile[tr + p * 8][tc] = src[(size_t)(r0 + tr + p * 8) * N + c0 + tc];
  __syncthreads();
  #pragma unroll
  for (int p = 0; p < 4; p++)
    dst[(size_t)(c0 + tr + p * 8) * ldk + r0 + tc] = f2bf(tile[tc][tr + p * 8]);
}

// one kernel for all 6 weight transposes (saves 5 launches)
__global__ __launch_bounds__(256) void prep_kernel(const float* Wq, const float* Wk,
                                                   const float* Wv, const float* Wo,
                                                   const float* W1, const float* W2,
                                                   u16* wqkv_t, u16* wo_t,
                                                   u16* w1_t, u16* w2_t) {
  int id = blockIdx.x;
  if (id < 4096) {
    const float* s = (id < 1024) ? Wq : (id < 2048) ? Wk : (id < 3072) ? Wv : Wo;
    u16* d = (id < 1024) ? wqkv_t : (id < 2048) ? wqkv_t + 1024 * 1024
           : (id < 3072) ? wqkv_t + 2 * 1024 * 1024 : wo_t;
    int local = id & 1023;
    cvt_t_body(s, d, 1024, 1024, local & 31, local >> 5);
  } else if (id < 8192) {
    int local = id - 4096;
    cvt_t_body(W1, w1_t, 4096, 1024, local & 127, local >> 7);
  } else {
    int local = id - 8192;
    cvt_t_body(W2, w2_t, 1024, 4096, local & 31, local >> 5);
  }
}

// ---------------- LayerNorm, one wave per row; IN_BF16 selects input dtype ----------------
template <int IN_BF16>
__global__ __launch_bounds__(256) void ln_kernel(const void* __restrict__ xv,
                                                 const float* __restrict__ g,
                                                 const float* __restrict__ be,
                                                 u16* __restrict__ out) {
  int wave = threadIdx.x >> 6, lane = threadIdx.x & 63;
  int row = blockIdx.x * 4 + wave;
  float v[16];
  float s = 0.f;
  if (IN_BF16) {
    const u16* xr = (const u16*)xv + (size_t)row * EMB;
    #pragma unroll
    for (int i = 0; i < 4; i++) {
      ushort4 u = *(const ushort4*)(xr + i * 256 + lane * 4);
      v[i * 4 + 0] = bf2f(u.x); v[i * 4 + 1] = bf2f(u.y);
      v[i * 4 + 2] = bf2f(u.z); v[i * 4 + 3] = bf2f(u.w);
      s += v[i * 4] + v[i * 4 + 1] + v[i * 4 + 2] + v[i * 4 + 3];
    }
  } else {
    const float* xr = (const float*)xv + (size_t)row * EMB;
    #pragma unroll
    for (int i = 0; i < 4; i++) {
      float4 u = *(const float4*)(xr + i * 256 + lane * 4);
      v[i * 4 + 0] = u.x; v[i * 4 + 1] = u.y; v[i * 4 + 2] = u.z; v[i * 4 + 3] = u.w;
      s += u.x + u.y + u.z + u.w;
    }
  }
  #pragma unroll
  for (int m = 1; m < 64; m <<= 1) s += __shfl_xor(s, m, 64);
  float mean = s * (1.f / EMB);
  float vs = 0.f;
  #pragma unroll
  for (int i = 0; i < 16; i++) { float dx = v[i] - mean; vs += dx * dx; }
  #pragma unroll
  for (int m = 1; m < 64; m <<= 1) vs += __shfl_xor(vs, m, 64);
  float inv = rsqrtf(vs * (1.f / EMB) + 1e-5f);
  u16* orow = out + (size_t)row * EMB;
  #pragma unroll
  for (int i = 0; i < 4; i++) {
    int c = i * 256 + lane * 4;
    float4 gv = *(const float4*)(g + c);
    float4 bv = *(const float4*)(be + c);
    ushort4 o;
    o.x = f2bf(gv.x * (v[i * 4 + 0] - mean) * inv + bv.x);
    o.y = f2bf(gv.y * (v[i * 4 + 1] - mean) * inv + bv.y);
    o.z = f2bf(gv.z * (v[i * 4 + 2] - mean) * inv + bv.z);
    o.w = f2bf(gv.w * (v[i * 4 + 3] - mean) * inv + bv.w);
    *(ushort4*)(orow + c) = o;
  }
}

// ---------------- 256x128 bf16 MFMA GEMM, BK=64, XOR swizzle, 512 thr ----------------
// MODE 1: fused-QKV (q,k -> [bh][s][d], v -> [bh][d][s]); MODE 2: +bias GELU bf16 out
template <int MODE>
__global__ __launch_bounds__(512) void gemm256(const u16* __restrict__ A,
                                               const u16* __restrict__ Bt,
                                               const float* __restrict__ bias,
                                               void* __restrict__ outp,
                                               int N, int K) {
  __shared__ __align__(16) u16 As[256 * 64];
  __shared__ __align__(16) u16 Bs[128 * 64];
  const int t = threadIdx.x;
  const int w = t >> 6, lane = t & 63;
  const int l15 = lane & 15, quad = lane >> 4;
  const int wr = w >> 1, wc = w & 1;
  const int rowBase = blockIdx.y * 256, colBase = blockIdx.x * 128;

  const int sr = lane >> 3;
  const int sc = ((lane & 7) ^ sr) * 8;
  const u16* gA = A + (size_t)(rowBase + w * 8 + sr) * K + sc;
  const u16* gB = Bt + (size_t)(colBase + w * 8 + sr) * K + sc;
  u16* lA = As + w * 8 * 64;
  u16* lB = Bs + w * 8 * 64;

  const int swz0 = (quad ^ (l15 & 7)) * 8;
  const int swz1 = ((quad + 4) ^ (l15 & 7)) * 8;

  f32x4 zero = {0.f, 0.f, 0.f, 0.f};
  f32x4 acc[4][4];
  #pragma unroll
  for (int i = 0; i < 4; i++)
    #pragma unroll
    for (int j = 0; j < 4; j++) acc[i][j] = zero;

  for (int k0 = 0; k0 < K; k0 += 64) {
    __syncthreads();
    #pragma unroll
    for (int j = 0; j < 4; j++)
      glds16(gA + (size_t)(j * 64) * K + k0, lA + j * 64 * 64);
    #pragma unroll
    for (int j = 0; j < 2; j++)
      glds16(gB + (size_t)(j * 64) * K + k0, lB + j * 64 * 64);
    __syncthreads();
    #pragma unroll
    for (int kk = 0; kk < 2; kk++) {
      const int so = kk ? swz1 : swz0;
      frag_u a4[4], b4[4];
      #pragma unroll
      for (int mi = 0; mi < 4; mi++)
        a4[mi].u4 = *(const uint4*)(As + (wr * 64 + mi * 16 + l15) * 64 + so);
      #pragma unroll
      for (int ni = 0; ni < 4; ni++)
        b4[ni].u4 = *(const uint4*)(Bs + (wc * 64 + ni * 16 + l15) * 64 + so);
      #pragma unroll
      for (int mi = 0; mi < 4; mi++)
        #pragma unroll
        for (int ni = 0; ni < 4; ni++)
          acc[mi][ni] = __builtin_amdgcn_mfma_f32_16x16x32_bf16(a4[mi].bf, b4[ni].bf, acc[mi][ni], 0, 0, 0);
    }
  }

  #pragma unroll
  for (int mi = 0; mi < 4; mi++) {
    #pragma unroll
    for (int ni = 0; ni < 4; ni++) {
      int col = colBase + wc * 64 + ni * 16 + l15;
      int row0 = rowBase + wr * 64 + mi * 16 + quad * 4;
      if (MODE == 1) {
        int mat = col >> 10, cc = col & 1023;
        int hh = cc >> 6, d = cc & 63;
        int b = row0 >> 11, s0 = row0 & 2047;
        if (mat == 2) {
          uint2 pk;
          pk.x = (unsigned)f2bf(acc[mi][ni][0]) | ((unsigned)f2bf(acc[mi][ni][1]) << 16);
          pk.y = (unsigned)f2bf(acc[mi][ni][2]) | ((unsigned)f2bf(acc[mi][ni][3]) << 16);
          *(uint2*)((u16*)outp + 2 * (size_t)TOK * EMB +
                    ((size_t)((b * NH + hh) * DH + d)) * SEQ + s0) = pk;
        } else {
          #pragma unroll
          for (int r = 0; r < 4; r++)
            ((u16*)outp)[(size_t)mat * (TOK * EMB) +
                         (((size_t)(b * NH + hh) * SEQ + s0 + r) << 6) + d] = f2bf(acc[mi][ni][r]);
        }
      } else {
        #pragma unroll
        for (int r = 0; r < 4; r++) {
          float vv = gelu_fast(acc[mi][ni][r] + bias[col]);
          ((u16*)outp)[(size_t)(row0 + r) * N + col] = f2bf(vv);
        }
      }
    }
  }
}

// ---------------- 128x128 GEMM (BK=64, swizzle) for Wo / FFN2 ----------------
// MODE 3: +bias +fp32 resid -> bf16 out; MODE 4: +bias +bf16 resid -> fp32 out
template <int MODE>
__global__ __launch_bounds__(256) void gemm128(const u16* __restrict__ A,
                                               const u16* __restrict__ Bt,
                                               const float* __restrict__ bias,
                                               const void* __restrict__ resid,
                                               void* __restrict__ outp,
                                               int N, int K) {
  __shared__ __align__(16) u16 As[128 * 64];
  __shared__ __align__(16) u16 Bs[128 * 64];
  const int t = threadIdx.x;
  const int w = t >> 6, lane = t & 63;
  const int l15 = lane & 15, quad = lane >> 4;
  const int wr = w >> 1, wc = w & 1;
  const int rowBase = blockIdx.y * 128, colBase = blockIdx.x * 128;

  const int sr = lane >> 3;
  const int sc = ((lane & 7) ^ sr) * 8;
  const u16* gA = A + (size_t)(rowBase + w * 8 + sr) * K + sc;
  const u16* gB = Bt + (size_t)(colBase + w * 8 + sr) * K + sc;
  u16* lA = As + w * 8 * 64;
  u16* lB = Bs + w * 8 * 64;

  const int swz0 = (quad ^ (l15 & 7)) * 8;
  const int swz1 = ((quad + 4) ^ (l15 & 7)) * 8;

  f32x4 zero = {0.f, 0.f, 0.f, 0.f};
  f32x4 acc[4][4];
  #pragma unroll
  for (int i = 0; i < 4; i++)
    #pragma unroll
    for (int j = 0; j < 4; j++) acc[i][j] = zero;

  for (int k0 = 0; k0 < K; k0 += 64) {
    __syncthreads();
    #pragma unroll
    for (int j = 0; j < 4; j++) {
      glds16(gA + (size_t)(j * 32) * K + k0, lA + j * 32 * 64);
      glds16(gB + (size_t)(j * 32) * K + k0, lB + j * 32 * 64);
    }
    __syncthreads();
    #pragma unroll
    for (int kk = 0; kk < 2; kk++) {
      const int so = kk ? swz1 : swz0;
      frag_u a4[4], b4[4];
      #pragma unroll
      for (int mi = 0; mi < 4; mi++)
        a4[mi].u4 = *(const uint4*)(As + (wr * 64 + mi * 16 + l15) * 64 + so);
      #pragma unroll
      for (int ni = 0; ni < 4; ni++)
        b4[ni].u4 = *(const uint4*)(Bs + (wc * 64 + ni * 16 + l15) * 64 + so);
      #pragma unroll
      for (int mi = 0; mi < 4; mi++)
        #pragma unroll
        for (int ni = 0; ni < 4; ni++)
          acc[mi][ni] = __builtin_amdgcn_mfma_f32_16x16x32_bf16(a4[mi].bf, b4[ni].bf, acc[mi][ni], 0, 0, 0);
    }
  }

  #pragma unroll
  for (int mi = 0; mi < 4; mi++) {
    #pragma unroll
    for (int ni = 0; ni < 4; ni++) {
      int col = colBase + wc * 64 + ni * 16 + l15;
      int row0 = rowBase + wr * 64 + mi * 16 + quad * 4;
      #pragma unroll
      for (int r = 0; r < 4; r++) {
        int row = row0 + r;
        float vv = acc[mi][ni][r] + bias[col];
        if (MODE == 3) {
          vv += ((const float*)resid)[(size_t)row * N + col];
          ((u16*)outp)[(size_t)row * N + col] = f2bf(vv);
        } else {
          vv += bf2f(((const u16*)resid)[(size_t)row * N + col]);
          ((float*)outp)[(size_t)row * N + col] = vv;
        }
      }
    }
  }
}

// ---------------- flash attention v3: S^T formulation, paired q-tiles ----------------
__global__ __launch_bounds__(256) void attn_kernel(const u16* __restrict__ q,
                                                   const u16* __restrict__ k,
                                                   const u16* __restrict__ vt,
                                                   u16* __restrict__ ctx) {
  __shared__ __align__(16) u16 Ks[64 * 72];
  __shared__ __align__(16) u16 Vs[64 * 72];
  __shared__ __align__(16) u16 Ps[128 * 72];
  __shared__ float Ls[128];
  const int t = threadIdx.x;
  const int w = t >> 6, lane = t & 63;
  const int l15 = lane & 15, quad = lane >> 4;
  const int bh = blockIdx.x, pr_ = blockIdx.y;
  const size_t base = (size_t)bh * SEQ * DH;
  const int bq = bh >> 4, hh = bh & 15;

  const int sr = t >> 2, scol = (t & 3) * 8;
  const u16* gK = k + base + (size_t)sr * DH + scol;
  const u16* gV = vt + base + (size_t)sr * SEQ + scol;
  u16* sK = Ks + sr * 72 + scol;
  u16* sV = Vs + sr * 72 + scol;

  f32x4 zero = {0.f, 0.f, 0.f, 0.f};
  uint4 rK0, rK1, rV0, rV1;
  rK0 = *(const uint4*)(gK);
  rK1 = *(const uint4*)(gK + 32);
  rV0 = *(const uint4*)(gV);
  rV1 = *(const uint4*)(gV + 32);

  for (int ti = 0; ti < 2; ti++) {
    const int qt = ti ? (15 - pr_) : pr_;
    const int qBase = qt * 128;
    const int ktEnd = 2 * qt + 1;

    frag_u qf[2][2];
    #pragma unroll
    for (int ni = 0; ni < 2; ni++)
      #pragma unroll
      for (int ks = 0; ks < 2; ks++)
        qf[ni][ks].u4 = *(const uint4*)(q + base +
            (size_t)(qBase + w * 32 + ni * 16 + l15) * DH + ks * 32 + quad * 8);

    f32x4 oacc[2][4];
    #pragma unroll
    for (int mi = 0; mi < 2; mi++)
      #pragma unroll
      for (int n0 = 0; n0 < 4; n0++) oacc[mi][n0] = zero;
    float l0 = 0.f, l1 = 0.f;

    for (int kt = 0; kt <= ktEnd; kt++) {
      __syncthreads();
      *(uint4*)sK = rK0; *(uint4*)(sK + 32) = rK1;
      *(uint4*)sV = rV0; *(uint4*)(sV + 32) = rV1;
      __syncthreads();
      int nkt = (kt < ktEnd) ? kt + 1 : (ti == 0 ? 0 : -1);
      if (nkt >= 0) {
        rK0 = *(const uint4*)(gK + (size_t)(nkt * 64) * DH);
        rK1 = *(const uint4*)(gK + (size_t)(nkt * 64) * DH + 32);
        rV0 = *(const uint4*)(gV + nkt * 64);
        rV1 = *(const uint4*)(gV + nkt * 64 + 32);
      }
      const int rel = kt - 2 * qt;
      if (rel == 1 && w < 2) continue;

      frag_u kf[4][2];
      #pragma unroll
      for (int mi = 0; mi < 4; mi++)
        #pragma unroll
        for (int ks = 0; ks < 2; ks++)
          kf[mi][ks].u4 = *(const uint4*)(Ks + (mi * 16 + l15) * 72 + ks * 32 + quad * 8);
      f32x4 st[4][2];
      #pragma unroll
      for (int mi = 0; mi < 4; mi++)
        #pragma unroll
        for (int ni = 0; ni < 2; ni++) st[mi][ni] = zero;
      #pragma unroll
      for (int ks = 0; ks < 2; ks++)
        #pragma unroll
        for (int mi = 0; mi < 4; mi++)
          #pragma unroll
          for (int ni = 0; ni < 2; ni++)
            st[mi][ni] = __builtin_amdgcn_mfma_f32_16x16x32_bf16(kf[mi][ks].bf, qf[ni][ks].bf, st[mi][ni], 0, 0, 0);

      const bool doMask = (rel == 0 && w < 2) || (rel == 1);
      #pragma unroll
      for (int ni = 0; ni < 2; ni++) {
        const int qrow = qBase + w * 32 + ni * 16 + l15;
        float sum = 0.f;
        u16* prow = Ps + (w * 32 + ni * 16 + l15) * 72;
        #pragma unroll
        for (int mi = 0; mi < 4; mi++) {
          float p[4];
          #pragma unroll
          for (int r = 0; r < 4; r++) {
            p[r] = __expf(st[mi][ni][r] * 0.125f);
            if (doMask && (kt * 64 + mi * 16 + quad * 4 + r) > qrow) p[r] = 0.f;
            sum += p[r];
          }
          uint2 pk;
          pk.x = (unsigned)f2bf(p[0]) | ((unsigned)f2bf(p[1]) << 16);
          pk.y = (unsigned)f2bf(p[2]) | ((unsigned)f2bf(p[3]) << 16);
          *(uint2*)(prow + mi * 16 + quad * 4) = pk;
        }
        sum += __shfl_xor(sum, 16, 64);
        sum += __shfl_xor(sum, 32, 64);
        if (ni == 0) l0 += sum; else l1 += sum;
      }

      frag_u pa[2][2];
      #pragma unroll
      for (int mi = 0; mi < 2; mi++)
        #pragma unroll
        for (int ks = 0; ks < 2; ks++)
          pa[mi][ks].u4 = *(const uint4*)(Ps + (w * 32 + mi * 16 + l15) * 72 + ks * 32 + quad * 8);
      #pragma unroll
      for (int ks = 0; ks < 2; ks++)
        #pragma unroll
        for (int n0 = 0; n0 < 4; n0++) {
          frag_u b;
          b.u4 = *(const uint4*)(Vs + (n0 * 16 + l15) * 72 + ks * 32 + quad * 8);
          #pragma unroll
          for (int mi = 0; mi < 2; mi++)
            oacc[mi][n0] = __builtin_amdgcn_mfma_f32_16x16x32_bf16(pa[mi][ks].bf, b.bf, oacc[mi][n0], 0, 0, 0);
        }
    }

    if (quad == 0) {
      Ls[w * 32 + l15] = l0;
      Ls[w * 32 + 16 + l15] = l1;
    }
    #pragma unroll
    for (int mi = 0; mi < 2; mi++) {
      float il[4];
      #pragma unroll
      for (int r = 0; r < 4; r++) il[r] = 1.f / Ls[w * 32 + mi * 16 + quad * 4 + r];
      #pragma unroll
      for (int n0 = 0; n0 < 4; n0++) {
        int s = qBase + w * 32 + mi * 16 + quad * 4;
        int col = hh * 64 + n0 * 16 + l15;
        #pragma unroll
        for (int r = 0; r < 4; r++)
          ctx[((size_t)(bq * SEQ + s + r)) * EMB + col] = f2bf(oacc[mi][n0][r] * il[r]);
      }
    }
  }
}

extern "C" void kernel_launch(void* const* d_in, const int* in_sizes, int n_in,
                              void* d_out, int out_size, void* d_ws, size_t ws_size,
                              hipStream_t stream) {
  const float* x  = (const float*)d_in[0];
  const float* Wq = (const float*)d_in[1];
  const float* Wk = (const float*)d_in[2];
  const float* Wv = (const float*)d_in[3];
  const float* Wo = (const float*)d_in[4];
  const float* bo = (const float*)d_in[5];
  const float* W1 = (const float*)d_in[6];
  const float* b1 = (const float*)d_in[7];
  const float* W2 = (const float*)d_in[8];
  const float* b2 = (const float*)d_in[9];
  const float* g1  = (const float*)d_in[10];
  const float* be1 = (const float*)d_in[11];
  const float* g2  = (const float*)d_in[12];
  const float* be2 = (const float*)d_in[13];
  float* out = (float*)d_out;
  char* ws = (char*)d_ws;
  const size_t MB = 1u << 20;

  u16* wqkv_t = (u16*)(ws + 0 * MB);          // 6 MB
  u16* wo_t   = (u16*)(ws + 6 * MB);          // 2 MB
  u16* w1_t   = (u16*)(ws + 8 * MB);          // 8 MB
  u16* w2_t   = (u16*)(ws + 16 * MB);         // 8 MB
  u16* hbuf   = (u16*)(ws + 24 * MB);         // 16 MB bf16 residual h
  u16* r1 = (u16*)(ws + 56 * MB);             // 16 MB: xn1 -> ctx -> xn2
  u16* qb = (u16*)(ws + 72 * MB);             // q,k 16 MB each; vt 16 MB [bh][d][s]
  u16* f1 = (u16*)(ws + 72 * MB);             // 64 MB, overlaps q/k/vt (dead after attn)

  // 1. all weights -> bf16 transposed (one dispatch)
  prep_kernel<<<12288, 256, 0, stream>>>(Wq, Wk, Wv, Wo, W1, W2,
                                         wqkv_t, wo_t, w1_t, w2_t);

  // 2. LN1(x) -> xn1
  ln_kernel<0><<<2048, 256, 0, stream>>>(x, g1, be1, r1);

  // 3. fused QKV (256x128 tiles); q,k row-major, v transposed to [bh][d][s]
  gemm256<1><<<dim3(24, 32), 512, 0, stream>>>(r1, wqkv_t, nullptr, qb, 3072, 1024);

  // 4. causal attention -> ctx
  attn_kernel<<<dim3(64, 8), 256, 0, stream>>>(qb, qb + (size_t)TOK * EMB,
                                               qb + 2 * (size_t)TOK * EMB, r1);

  // 5. Wo + bo + x -> h (bf16)
  gemm128<3><<<dim3(8, 64), 256, 0, stream>>>(r1, wo_t, bo, x, hbuf, 1024, 1024);

  // 6. LN2(h) -> xn2
  ln_kernel<1><<<2048, 256, 0, stream>>>(hbuf, g2, be2, r1);

  // 7. FFN1: GELU(xn2 @ W1 + b1) -> f1 (256x128 tiles)
  gemm256<2><<<dim3(32, 32), 512, 0, stream>>>(r1, w1_t, b1, f1, 4096, 1024);

  // 8. FFN2: f1 @ W2 + b2 + h -> out (fp32)
  gemm128<4><<<dim3(8, 64), 256, 0, stream>>>(f1, w2_t, b2, hbuf, out, 1024, 4096);
}